// Round 4
// baseline (5441.035 us; speedup 1.0000x reference)
//
#include <hip/hip_runtime.h>
#include <hip/hip_bf16.h>

typedef __attribute__((ext_vector_type(8))) short bh8;   // 8 x bf16 (4 VGPRs)
typedef __attribute__((ext_vector_type(4))) float f4;    // MFMA accumulator

static constexpr int T_STEPS = 128;
static constexpr int BTOT    = 2048;
static constexpr int HD      = 256;
static constexpr int NG      = 768;   // 3*H
static constexpr int LOUT    = 100;
static constexpr int LDS_STRIDE = 264; // 256 + 8 pad (bf16) -> conflict-free ds_read_b128

#define SBAR() __builtin_amdgcn_sched_barrier(0)

__device__ __forceinline__ short f2bf(float f){
  unsigned u = __builtin_bit_cast(unsigned, f);
  unsigned r = (u + 0x7FFFu + ((u >> 16) & 1u)) >> 16;   // RNE
  return (short)(unsigned short)r;
}
__device__ __forceinline__ float bf2f(short s){
  unsigned u = ((unsigned)(unsigned short)s) << 16;
  return __builtin_bit_cast(float, u);
}

__device__ __forceinline__ f4 mfma16(bh8 a, bh8 b, f4 c){
  return __builtin_amdgcn_mfma_f32_16x16x32_bf16(a, b, c, 0, 0, 0);
}

__device__ __forceinline__ float sigm(float x){
  return __builtin_amdgcn_rcpf(1.f + __expf(-x));
}
__device__ __forceinline__ float tanh_f(float x){
  return 1.f - 2.f*__builtin_amdgcn_rcpf(1.f + __expf(2.f*x));
}

// ---------------- prep: E0 = emb @ w_ih0^T + b_ih0  ([64][768] f32) ----------------
__global__ void e0_kernel(const float* __restrict__ emb, const float* __restrict__ w_ih0,
                          const float* __restrict__ b_ih0, float* __restrict__ E0)
{
  int tid = blockIdx.x*blockDim.x + threadIdx.x;
  if (tid >= 64*NG) return;
  int v = tid / NG, n = tid % NG;
  const float4* er = (const float4*)(emb + (size_t)v*HD);
  const float4* wr = (const float4*)(w_ih0 + (size_t)n*HD);
  float s = 0.f;
#pragma unroll 4
  for (int k=0;k<HD/4;++k){
    float4 a = er[k], b = wr[k];
    s += a.x*b.x + a.y*b.y + a.z*b.z + a.w*b.w;
  }
  E0[tid] = s + b_ih0[n];
}

// ---------------- prep: pack all weights into B-fragment-linear bf16 tiles ----------------
// (verified in rounds 1-3)
__global__ void pack_kernel(const float* __restrict__ w_hh0, const float* __restrict__ w_ih1,
                            const float* __restrict__ w_hh1, const float* __restrict__ w1,
                            const float* __restrict__ w2, short* __restrict__ pack)
{
  int tid = blockIdx.x*blockDim.x + threadIdx.x;
  if (tid >= 1336*64) return;
  int t = tid >> 6, lane = tid & 63;
  int l15 = lane & 15, lq = lane >> 4;
  const float* src = nullptr;
  bool zero = false;
  if (t < 384){
    int w = t/48, rem = t%48, i = rem/8, kt = rem%8;
    int n = (i>>1)*256 + w*32 + (i&1)*16 + l15;
    src = w_hh0 + (size_t)n*HD + kt*32 + lq*8;
  } else if (t < 1152){
    int tt = t - 384, w = tt/96, rem = tt%96, i = rem/16, kt = rem%16;
    int n = (i>>1)*256 + w*32 + (i&1)*16 + l15;
    src = (kt < 8) ? (w_ih1 + (size_t)n*HD + kt*32 + lq*8)
                   : (w_hh1 + (size_t)n*HD + (kt-8)*32 + lq*8);
  } else if (t < 1280){
    int tt = t - 1152, w = tt/16, rem = tt%16, ntt = rem/8, kt = rem%8;
    int n = w*32 + ntt*16 + l15;
    src = w1 + (size_t)n*HD + kt*32 + lq*8;
  } else {
    int tt = t - 1280, ntt = tt/8, kt = tt%8;
    int n = ntt*16 + l15;
    if (n < LOUT) src = w2 + (size_t)n*HD + kt*32 + lq*8;
    else zero = true;
  }
  bh8 o;
#pragma unroll
  for (int e=0;e<8;++e) o[e] = zero ? (short)0 : f2bf(src[e]);
  ((bh8*)pack)[tid] = o;
}

// ---------------- main: fused 2-layer GRU scan + head, 1 wg = 32 batch rows ----------------
// Round 4: explicit software pipeline. Double-buffered named B-chunks with
// sched_barrier(0) pinning so >=6 weight loads stay in flight (counted vmcnt),
// E0 gathers prefetched at step top, tokens prefetched one step ahead.
__global__ __launch_bounds__(512, 1)
void rnn_main(const int* __restrict__ tokens, const int* __restrict__ lens,
              const float* __restrict__ E0, const short* __restrict__ pack,
              const float* __restrict__ b_hh0, const float* __restrict__ b_ih1,
              const float* __restrict__ b_hh1, const float* __restrict__ b1,
              const float* __restrict__ b2, float* __restrict__ out)
{
  const int tid  = threadIdx.x;
  const int wid  = tid >> 6;      // wave 0..7, owns gate-cols [32*wid, 32*wid+32)
  const int lane = tid & 63;
  const int l15  = lane & 15;
  const int lq   = lane >> 4;
  const int b0   = blockIdx.x * 32;

  __shared__ __align__(16) short s0_lds[32*LDS_STRIDE];      // layer0 state (bf16)
  __shared__ __align__(16) short s1_lds[2][32*LDS_STRIDE];   // layer1 state, dbl-buffered
  __shared__ float bias0[NG], biasI1[NG], biasH1[NG], b1s[HD], b2s[112];

  for (int i = tid; i < 32*LDS_STRIDE; i += 512){
    s0_lds[i] = 0; s1_lds[0][i] = 0; s1_lds[1][i] = 0;
  }
  for (int i = tid; i < NG; i += 512){ bias0[i] = b_hh0[i]; biasI1[i] = b_ih1[i]; biasH1[i] = b_hh1[i]; }
  if (tid < HD)  b1s[tid] = b1[tid];
  if (tid < 112) b2s[tid] = (tid < LOUT) ? b2[tid] : 0.f;

  int mylens[2][4];
#pragma unroll
  for (int rt=0;rt<2;++rt)
#pragma unroll
    for (int r=0;r<4;++r) mylens[rt][r] = lens[b0 + rt*16 + lq*4 + r];

  float h1s[2][2][4], outf[2][2][4];   // [rt][nt][r4]
#pragma unroll
  for (int rt=0;rt<2;++rt)
#pragma unroll
    for (int nt=0;nt<2;++nt)
#pragma unroll
      for (int r=0;r<4;++r){ h1s[rt][nt][r]=0.f; outf[rt][nt][r]=0.f; }

  const bh8* __restrict__ packL0 = (const bh8*)pack + (size_t)(       wid*48)*64 + lane;
  const bh8* __restrict__ packL1 = (const bh8*)pack + (size_t)( 384 + wid*96)*64 + lane;
  const bh8* __restrict__ packW1 = (const bh8*)pack + (size_t)(1152 + wid*16)*64 + lane;
  const bh8* __restrict__ packW2 = (const bh8*)pack + (size_t)(1280 + wid*8 )*64 + lane;

  const int afrag = l15*LDS_STRIDE + lq*8;     // A-frag base offset: row l15, k0 = lq*8
  const short* s0p = &s0_lds[afrag];
  constexpr int RT1 = 16*LDS_STRIDE;           // second row-tile offset (elems)

  const f4 zf = {0.f, 0.f, 0.f, 0.f};

  // token prefetch for t=0
  int tokr[2][4];
#pragma unroll
  for (int rt=0;rt<2;++rt)
#pragma unroll
    for (int r=0;r<4;++r) tokr[rt][r] = tokens[0*BTOT + b0 + rt*16 + lq*4 + r];

  __syncthreads();

#pragma unroll 1
  for (int t = 0; t < T_STEPS; ++t){
    // ---- prefetch next step's tokens + this step's E0 gather values ----
    int tokn[2][4];
    if (t < T_STEPS-1){
#pragma unroll
      for (int rt=0;rt<2;++rt)
#pragma unroll
        for (int r=0;r<4;++r) tokn[rt][r] = tokens[(t+1)*BTOT + b0 + rt*16 + lq*4 + r];
    } else {
#pragma unroll
      for (int rt=0;rt<2;++rt)
#pragma unroll
        for (int r=0;r<4;++r) tokn[rt][r] = 0;
    }
    float e0v[2][2][4][3];   // [rt][nt][r4][gate]
#pragma unroll
    for (int rt=0;rt<2;++rt)
#pragma unroll
      for (int nt=0;nt<2;++nt){
        const int jb = wid*32 + nt*16 + l15;
#pragma unroll
        for (int r4=0;r4<4;++r4){
          const float* p = E0 + (size_t)tokr[rt][r4]*NG + jb;
          e0v[rt][nt][r4][0] = p[0];
          e0v[rt][nt][r4][1] = p[256];
          e0v[rt][nt][r4][2] = p[512];
        }
      }
    SBAR();

    // ---- layer 0 GEMM: gh0 = s0 @ w_hh0^T (K=256), pipelined B-chunks ----
    f4 acc0[6][2];
#pragma unroll
    for (int i=0;i<6;++i){ acc0[i][0]=zf; acc0[i][1]=zf; }
    bh8 bb[2][6];
#pragma unroll
    for (int i=0;i<6;++i) bb[0][i] = packL0[(i*8)*64];
#pragma unroll
    for (int kt=0;kt<8;++kt){
      if (kt < 7){
#pragma unroll
        for (int i=0;i<6;++i) bb[(kt+1)&1][i] = packL0[(i*8+kt+1)*64];
      }
      SBAR();   // loads above stay above; MFMAs below wait with counted vmcnt
      bh8 a0 = *(const bh8*)(s0p + kt*32);
      bh8 a1 = *(const bh8*)(s0p + RT1 + kt*32);
#pragma unroll
      for (int i=0;i<6;++i){
        acc0[i][0] = mfma16(a0, bb[kt&1][i], acc0[i][0]);
        acc0[i][1] = mfma16(a1, bb[kt&1][i], acc0[i][1]);
      }
    }
    __syncthreads();  // A: all waves done reading s0_lds

    // ---- layer 0 epilogue: h0 carried as bf16 in LDS ----
#pragma unroll
    for (int rt=0;rt<2;++rt){
#pragma unroll
      for (int nt=0;nt<2;++nt){
        const int jb = wid*32 + nt*16 + l15;
        const float bhr = bias0[jb], bhz = bias0[256+jb], bhn = bias0[512+jb];
#pragma unroll
        for (int r4=0;r4<4;++r4){
          const int brow = rt*16 + lq*4 + r4;
          const float rg = sigm(acc0[0+nt][rt][r4] + bhr + e0v[rt][nt][r4][0]);
          const float zg = sigm(acc0[2+nt][rt][r4] + bhz + e0v[rt][nt][r4][1]);
          const float ng = tanh_f(e0v[rt][nt][r4][2] + rg*(acc0[4+nt][rt][r4] + bhn));
          const float ho = bf2f(s0_lds[brow*LDS_STRIDE + jb]);   // h0_{t-1}, thread-private loc
          const float h = ng + zg*(ho - ng);
          s0_lds[brow*LDS_STRIDE + jb] = f2bf(h);
        }
      }
    }
    __syncthreads();  // B: s0_lds now holds s0_t

    // ---- layer 1 GEMM: A = [s0_t | s1_{t-1}], K=512, pipelined B-chunks ----
    const short* s1r = &s1_lds[t & 1][afrag];          // read buffer (h1_{t-1})
    short*       s1w = &s1_lds[(t + 1) & 1][0];        // write buffer (h1_t)
    f4 ar_[2][2], az_[2][2], ani[2][2], anh[2][2];     // [nt][rt]
#pragma unroll
    for (int nt=0;nt<2;++nt){
      ar_[nt][0]=zf; ar_[nt][1]=zf; az_[nt][0]=zf; az_[nt][1]=zf;
      ani[nt][0]=zf; ani[nt][1]=zf; anh[nt][0]=zf; anh[nt][1]=zf;
    }
    bh8 cb[2][6];
#pragma unroll
    for (int nt=0;nt<2;++nt){
      cb[0][nt*3+0] = packL1[((0+nt)*16)*64];
      cb[0][nt*3+1] = packL1[((2+nt)*16)*64];
      cb[0][nt*3+2] = packL1[((4+nt)*16)*64];
    }
#pragma unroll
    for (int kt=0;kt<16;++kt){
      if (kt < 15){
#pragma unroll
        for (int nt=0;nt<2;++nt){
          cb[(kt+1)&1][nt*3+0] = packL1[((0+nt)*16+kt+1)*64];
          cb[(kt+1)&1][nt*3+1] = packL1[((2+nt)*16+kt+1)*64];
          cb[(kt+1)&1][nt*3+2] = packL1[((4+nt)*16+kt+1)*64];
        }
      }
      SBAR();
      const short* abase = (kt < 8) ? (s0p + kt*32) : (s1r + (kt-8)*32);
      bh8 a0 = *(const bh8*)abase;
      bh8 a1 = *(const bh8*)(abase + RT1);
#pragma unroll
      for (int nt=0;nt<2;++nt){
        ar_[nt][0] = mfma16(a0, cb[kt&1][nt*3+0], ar_[nt][0]);
        ar_[nt][1] = mfma16(a1, cb[kt&1][nt*3+0], ar_[nt][1]);
        az_[nt][0] = mfma16(a0, cb[kt&1][nt*3+1], az_[nt][0]);
        az_[nt][1] = mfma16(a1, cb[kt&1][nt*3+1], az_[nt][1]);
        if (kt < 8){
          ani[nt][0] = mfma16(a0, cb[kt&1][nt*3+2], ani[nt][0]);
          ani[nt][1] = mfma16(a1, cb[kt&1][nt*3+2], ani[nt][1]);
        } else {
          anh[nt][0] = mfma16(a0, cb[kt&1][nt*3+2], anh[nt][0]);
          anh[nt][1] = mfma16(a1, cb[kt&1][nt*3+2], anh[nt][1]);
        }
      }
    }

    // ---- layer 1 epilogue + output capture (writes other s1 buffer) ----
#pragma unroll
    for (int nt=0;nt<2;++nt){
      const int jb = wid*32 + nt*16 + l15;
      const float bir = biasI1[jb],     bhr = biasH1[jb];
      const float biz = biasI1[256+jb], bhz = biasH1[256+jb];
      const float bin = biasI1[512+jb], bhn = biasH1[512+jb];
#pragma unroll
      for (int rt=0;rt<2;++rt){
#pragma unroll
        for (int r4=0;r4<4;++r4){
          const int brow = rt*16 + lq*4 + r4;
          const float rg = sigm(ar_[nt][rt][r4] + bir + bhr);
          const float zg = sigm(az_[nt][rt][r4] + biz + bhz);
          const float ng = tanh_f((ani[nt][rt][r4] + bin) + rg*(anh[nt][rt][r4] + bhn));
          float h = h1s[rt][nt][r4];
          h = ng + zg*(h - ng);
          h1s[rt][nt][r4] = h;
          if (mylens[rt][r4] == t) outf[rt][nt][r4] = h;
          s1w[brow*LDS_STRIDE + jb] = f2bf(h);
        }
      }
    }
#pragma unroll
    for (int rt=0;rt<2;++rt)
#pragma unroll
      for (int r=0;r<4;++r) tokr[rt][r] = tokn[rt][r];
    // no barrier: next iteration's barriers order LDS accesses
  }
  __syncthreads();  // loop done; safe to reuse LDS for the head

  // ---- head: z = LeakyReLU(out_t @ w1^T + b1); enc = z @ w2^T + b2 ----
#pragma unroll
  for (int rt=0;rt<2;++rt)
#pragma unroll
    for (int nt=0;nt<2;++nt){
      const int jb = wid*32 + nt*16 + l15;
#pragma unroll
      for (int r4=0;r4<4;++r4)
        s0_lds[(rt*16+lq*4+r4)*LDS_STRIDE + jb] = f2bf(outf[rt][nt][r4]);
    }
  __syncthreads();

  {
    f4 az[2][2]; az[0][0]=zf; az[0][1]=zf; az[1][0]=zf; az[1][1]=zf;
#pragma unroll
    for (int kt=0;kt<8;++kt){
      bh8 a0 = *(const bh8*)(s0p + kt*32);
      bh8 a1 = *(const bh8*)(s0p + RT1 + kt*32);
#pragma unroll
      for (int nt=0;nt<2;++nt){
        bh8 b = packW1[(nt*8+kt)*64];
        az[nt][0] = mfma16(a0, b, az[nt][0]);
        az[nt][1] = mfma16(a1, b, az[nt][1]);
      }
    }
#pragma unroll
    for (int rt=0;rt<2;++rt)
#pragma unroll
      for (int nt=0;nt<2;++nt){
        const int jb = wid*32 + nt*16 + l15;
#pragma unroll
        for (int r4=0;r4<4;++r4){
          float v = az[nt][rt][r4] + b1s[jb];
          v = (v >= 0.f) ? v : 0.01f*v;     // LeakyReLU
          s1_lds[0][(rt*16+lq*4+r4)*LDS_STRIDE + jb] = f2bf(v);
        }
      }
  }
  __syncthreads();

  if (wid < 7){
    const short* zp = &s1_lds[0][afrag];
    f4 acc2[2]; acc2[0]=zf; acc2[1]=zf;
#pragma unroll
    for (int kt=0;kt<8;++kt){
      bh8 a0 = *(const bh8*)(zp + kt*32);
      bh8 a1 = *(const bh8*)(zp + RT1 + kt*32);
      bh8 b = packW2[kt*64];
      acc2[0] = mfma16(a0, b, acc2[0]);
      acc2[1] = mfma16(a1, b, acc2[1]);
    }
    const int n2 = wid*16 + l15;
    if (n2 < LOUT){
#pragma unroll
      for (int rt=0;rt<2;++rt)
#pragma unroll
        for (int r4=0;r4<4;++r4)
          out[(size_t)(b0 + rt*16 + lq*4 + r4)*LOUT + n2] = acc2[rt][r4] + b2s[n2];
    }
  }
}

extern "C" void kernel_launch(void* const* d_in, const int* in_sizes, int n_in,
                              void* d_out, int out_size, void* d_ws, size_t ws_size,
                              hipStream_t stream)
{
  const int*   tokens = (const int*)  d_in[0];
  const int*   lens   = (const int*)  d_in[1];
  const float* emb    = (const float*)d_in[2];
  const float* w_ih0  = (const float*)d_in[3];
  const float* w_hh0  = (const float*)d_in[4];
  const float* b_ih0  = (const float*)d_in[5];
  const float* b_hh0  = (const float*)d_in[6];
  const float* w_ih1  = (const float*)d_in[7];
  const float* w_hh1  = (const float*)d_in[8];
  const float* b_ih1  = (const float*)d_in[9];
  const float* b_hh1  = (const float*)d_in[10];
  const float* w1     = (const float*)d_in[11];
  const float* b1     = (const float*)d_in[12];
  const float* w2     = (const float*)d_in[13];
  const float* b2     = (const float*)d_in[14];

  float* E0   = (float*)d_ws;                                  // 196608 B
  short* pack = (short*)((char*)d_ws + 64*NG*sizeof(float));   // 1336 KiB packed bf16 tiles

  e0_kernel  <<<(64*NG + 255)/256,   256, 0, stream>>>(emb, w_ih0, b_ih0, E0);
  pack_kernel<<<(1336*64 + 255)/256, 256, 0, stream>>>(w_hh0, w_ih1, w_hh1, w1, w2, pack);
  rnn_main   <<<64, 512, 0, stream>>>(tokens, lens, E0, pack,
                                      b_hh0, b_ih1, b_hh1, b1, b2, (float*)d_out);
}

// Round 5
// 1546.572 us; speedup vs baseline: 3.5181x; 3.5181x over previous
//
#include <hip/hip_runtime.h>
#include <hip/hip_bf16.h>

typedef __attribute__((ext_vector_type(8))) short bh8;   // 8 x bf16 (4 VGPRs)
typedef __attribute__((ext_vector_type(4))) float f4;    // MFMA accumulator

static constexpr int T_STEPS = 128;
static constexpr int BTOT    = 2048;
static constexpr int HD      = 256;
static constexpr int NG      = 768;   // 3*H
static constexpr int LOUT    = 100;

__device__ __forceinline__ short f2bf(float f){
  unsigned u = __builtin_bit_cast(unsigned, f);
  unsigned r = (u + 0x7FFFu + ((u >> 16) & 1u)) >> 16;   // RNE
  return (short)(unsigned short)r;
}
__device__ __forceinline__ float bf2f(short s){
  unsigned u = ((unsigned)(unsigned short)s) << 16;
  return __builtin_bit_cast(float, u);
}
__device__ __forceinline__ f4 mfma16(bh8 a, bh8 b, f4 c){
  return __builtin_amdgcn_mfma_f32_16x16x32_bf16(a, b, c, 0, 0, 0);
}
__device__ __forceinline__ float sigm(float x){
  return __builtin_amdgcn_rcpf(1.f + __expf(-x));
}
__device__ __forceinline__ float tanh_f(float x){
  return 1.f - 2.f*__builtin_amdgcn_rcpf(1.f + __expf(2.f*x));
}

// ---------------- prep: E0h = bf16(emb @ w_ih0^T + b_ih0)  ([64][768]) ----------------
__global__ void e0h_kernel(const float* __restrict__ emb, const float* __restrict__ w_ih0,
                           const float* __restrict__ b_ih0, short* __restrict__ E0h)
{
  int tid = blockIdx.x*blockDim.x + threadIdx.x;
  if (tid >= 64*NG) return;
  int v = tid / NG, n = tid % NG;
  const float4* er = (const float4*)(emb + (size_t)v*HD);
  const float4* wr = (const float4*)(w_ih0 + (size_t)n*HD);
  float s = 0.f;
#pragma unroll 4
  for (int k=0;k<HD/4;++k){
    float4 a = er[k], b = wr[k];
    s += a.x*b.x + a.y*b.y + a.z*b.z + a.w*b.w;
  }
  E0h[tid] = f2bf(s + b_ih0[n]);
}

// ---------------- prep: pack weights into fragment-linear bf16 tiles ----------------
// tile = 1KB = 64 lanes x 16B: value[lane][e] = W[n=ct*16+(lane&15)][k=kt*32+(lane>>4)*8+e]
// tiles 0..383   : w_hh0  [ct(48)][kt(8)]
// tiles 384..767 : w_ih1  [ct][kt]
// tiles 768..1151: w_hh1  [ct][kt]
// tiles 1152..1279: w1 [wid(8)][nt(2)][kt(8)]   (head, 8-wave layout - verified r1-3)
// tiles 1280..1335: w2 [ntt(7)][kt(8)] pad N 100->112
__global__ void pack_kernel(const float* __restrict__ w_hh0, const float* __restrict__ w_ih1,
                            const float* __restrict__ w_hh1, const float* __restrict__ w1,
                            const float* __restrict__ w2, short* __restrict__ pack)
{
  int tid = blockIdx.x*blockDim.x + threadIdx.x;
  if (tid >= 1336*64) return;
  int t = tid >> 6, lane = tid & 63;
  int l15 = lane & 15, lq = lane >> 4;
  const float* src = nullptr;
  bool zero = false;
  if (t < 1152){
    int m = t/384, tt = t%384, ct = tt/8, kt = tt%8;
    int n = ct*16 + l15;
    const float* Wm = (m==0) ? w_hh0 : (m==1 ? w_ih1 : w_hh1);
    src = Wm + (size_t)n*HD + kt*32 + lq*8;
  } else if (t < 1280){
    int tt = t - 1152, w = tt/16, rem = tt%16, ntt = rem/8, kt = rem%8;
    int n = w*32 + ntt*16 + l15;
    src = w1 + (size_t)n*HD + kt*32 + lq*8;
  } else {
    int tt = t - 1280, ntt = tt/8, kt = tt%8;
    int n = ntt*16 + l15;
    if (n < LOUT) src = w2 + (size_t)n*HD + kt*32 + lq*8;
    else zero = true;
  }
  bh8 o;
#pragma unroll
  for (int e=0;e<8;++e) o[e] = zero ? (short)0 : f2bf(src[e]);
  ((bh8*)pack)[tid] = o;
}

// ---------------- phase A: layer-0 scan, w_hh0 register-resident ----------------
// 128 wgs x 256 thr (4 waves, 1 wave/SIMD -> 512-reg budget). M=16 rows/wg.
// wave w owns hidden dims [64w,64w+64): accum tiles [g*4+c] over gates g, col-chunks c.
__global__ __launch_bounds__(256, 1)
void layer0_scan(const int* __restrict__ tokens, const short* __restrict__ E0h,
                 const short* __restrict__ pack, const float* __restrict__ b_hh0,
                 short* __restrict__ s0c, short* __restrict__ h0g, int tc, int Tc)
{
  const int tid = threadIdx.x;
  const int wid = tid >> 6;
  const int lane = tid & 63;
  const int l15 = lane & 15, lq = lane >> 4;
  const int b0 = blockIdx.x * 16;

  __shared__ __align__(16) short st[16*264];        // h0 state (bf16)
  __shared__ __align__(16) short ebuf[2][16*776];   // E0 rows staged (bf16), dbuf
  __shared__ float bh[NG];

  for (int i=tid;i<NG;i+=256) bh[i] = b_hh0[i];
  if (tc == 0){
    for (int i=tid;i<16*264;i+=256) st[i] = 0;
  } else {
    for (int i=tid;i<16*256;i+=256)
      st[(i>>8)*264 + (i&255)] = h0g[(size_t)(b0 + (i>>8))*HD + (i&255)];
  }

  // weights: 12 col-tiles x 8 k-tiles, register-resident
  bh8 W[12][8];
  const bh8* pt = (const bh8*)pack;
#pragma unroll
  for (int g=0;g<3;++g)
#pragma unroll
    for (int c=0;c<4;++c)
#pragma unroll
      for (int kt=0;kt<8;++kt)
        W[g*4+c][kt] = pt[(size_t)((g*16 + wid*4 + c)*8 + kt)*64 + lane];

  // prologue: stage E0 rows for t=0
  {
    const int tg = tc*Tc;
    bh8 sreg[6];
#pragma unroll
    for (int j=0;j<6;++j){
      int q = tid + j*256, row = q/96, col8 = (q%96)*8;
      int tok = tokens[(size_t)tg*BTOT + b0 + row];
      sreg[j] = *(const bh8*)(E0h + (size_t)tok*NG + col8);
    }
#pragma unroll
    for (int j=0;j<6;++j){
      int q = tid + j*256, row = q/96, col8 = (q%96)*8;
      *(bh8*)(&ebuf[0][row*776 + col8]) = sreg[j];
    }
  }
  __syncthreads();

  const f4 zf = {0.f,0.f,0.f,0.f};
  const short* sp = &st[l15*264 + lq*8];

#pragma unroll 1
  for (int t=0; t<Tc; ++t){
    const int tg = tc*Tc + t;
    const bool more = (t+1 < Tc);
    bh8 nreg[6];
    if (more){
#pragma unroll
      for (int j=0;j<6;++j){
        int q = tid + j*256, row = q/96, col8 = (q%96)*8;
        int tok = tokens[(size_t)(tg+1)*BTOT + b0 + row];
        nreg[j] = *(const bh8*)(E0h + (size_t)tok*NG + col8);
      }
    }
    // GEMM: gh0 = h0 @ w_hh0^T (96 MFMAs, zero loads)
    f4 acc[12];
#pragma unroll
    for (int i=0;i<12;++i) acc[i] = zf;
#pragma unroll
    for (int kt=0;kt<8;++kt){
      bh8 a = *(const bh8*)(sp + kt*32);
#pragma unroll
      for (int i=0;i<12;++i) acc[i] = mfma16(a, W[i][kt], acc[i]);
    }
    __syncthreads();   // all waves done reading st
    // epilogue
    const short* eb = ebuf[t&1];
#pragma unroll
    for (int c=0;c<4;++c){
      const int jh = wid*64 + c*16 + l15;
      const float bhr = bh[jh], bhz = bh[256+jh], bhn = bh[512+jh];
#pragma unroll
      for (int r4=0;r4<4;++r4){
        const int row = lq*4 + r4;
        const float er = bf2f(eb[row*776 + jh]);
        const float ez = bf2f(eb[row*776 + 256 + jh]);
        const float en = bf2f(eb[row*776 + 512 + jh]);
        const float rg = sigm(acc[c][r4]   + bhr + er);
        const float zg = sigm(acc[4+c][r4] + bhz + ez);
        const float ng = tanh_f(en + rg*(acc[8+c][r4] + bhn));
        const float ho = bf2f(st[row*264 + jh]);
        const float h  = ng + zg*(ho - ng);
        const short hb = f2bf(h);
        st[row*264 + jh] = hb;
        s0c[((size_t)t*BTOT + b0 + row)*HD + jh] = hb;
      }
    }
    if (more){
      short* wb = ebuf[(t+1)&1];
#pragma unroll
      for (int j=0;j<6;++j){
        int q = tid + j*256, row = q/96, col8 = (q%96)*8;
        *(bh8*)(&wb[row*776 + col8]) = nreg[j];
      }
    }
    __syncthreads();
  }
  for (int i=tid;i<16*256;i+=256)
    h0g[(size_t)(b0 + (i>>8))*HD + (i&255)] = st[(i>>8)*264 + (i&255)];
}

// ---------------- phase B: gi1 = s0 @ w_ih1^T + b_ih1 (parallel GEMM) ----------------
// 256 wgs x 256 thr; w_ih1 register-resident; 16-row chunks streamed through LDS.
__global__ __launch_bounds__(256, 1)
void gi1_gemm(const short* __restrict__ s0c, const short* __restrict__ pack,
              const float* __restrict__ b_ih1, short* __restrict__ gi1c, int NC)
{
  const int tid = threadIdx.x;
  const int wid = tid >> 6;
  const int lane = tid & 63;
  const int l15 = lane & 15, lq = lane >> 4;

  __shared__ __align__(16) short ab[2][16*264];
  __shared__ float bi[NG];
  for (int i=tid;i<NG;i+=256) bi[i] = b_ih1[i];

  bh8 W[12][8];
#pragma unroll
  for (int i=0;i<12;++i)
#pragma unroll
    for (int kt=0;kt<8;++kt)
      W[i][kt] = ((const bh8*)pack)[(size_t)(384 + (wid*12+i)*8 + kt)*64 + lane];

  int ci = blockIdx.x;
  if (ci >= NC) return;
  bh8 sr[2];
#pragma unroll
  for (int j=0;j<2;++j){
    int q = tid + j*256;
    sr[j] = *(const bh8*)(s0c + (size_t)ci*4096 + q*8);
  }
#pragma unroll
  for (int j=0;j<2;++j){
    int q = tid + j*256, row = q>>5, col8 = (q&31)*8;
    *(bh8*)(&ab[0][row*264 + col8]) = sr[j];
  }
  __syncthreads();

  const f4 zf = {0.f,0.f,0.f,0.f};
  int p = 0;
#pragma unroll 1
  for (; ci < NC; ci += gridDim.x){
    const int cin = ci + (int)gridDim.x;
    const bool more = (cin < NC);
    if (more){
#pragma unroll
      for (int j=0;j<2;++j){
        int q = tid + j*256;
        sr[j] = *(const bh8*)(s0c + (size_t)cin*4096 + q*8);
      }
    }
    f4 acc[12];
#pragma unroll
    for (int i=0;i<12;++i) acc[i] = zf;
    const short* sp = &ab[p][l15*264 + lq*8];
#pragma unroll
    for (int kt=0;kt<8;++kt){
      bh8 a = *(const bh8*)(sp + kt*32);
#pragma unroll
      for (int i=0;i<12;++i) acc[i] = mfma16(a, W[i][kt], acc[i]);
    }
#pragma unroll
    for (int i=0;i<12;++i){
      const int gc = (wid*12+i)*16 + l15;
      const float b = bi[gc];
#pragma unroll
      for (int r4=0;r4<4;++r4)
        gi1c[(size_t)(ci*16 + lq*4 + r4)*NG + gc] = f2bf(acc[i][r4] + b);
    }
    if (more){
#pragma unroll
      for (int j=0;j<2;++j){
        int q = tid + j*256, row = q>>5, col8 = (q&31)*8;
        *(bh8*)(&ab[p^1][row*264 + col8]) = sr[j];
      }
    }
    p ^= 1;
    __syncthreads();
  }
}

// ---------------- phase C: layer-1 scan, w_hh1 register-resident ----------------
__global__ __launch_bounds__(256, 1)
void layer1_scan(const int* __restrict__ lens, const short* __restrict__ gi1c,
                 const short* __restrict__ pack, const float* __restrict__ b_hh1,
                 short* __restrict__ h1g, float* __restrict__ outbuf, int tc, int Tc)
{
  const int tid = threadIdx.x;
  const int wid = tid >> 6;
  const int lane = tid & 63;
  const int l15 = lane & 15, lq = lane >> 4;
  const int b0 = blockIdx.x * 16;

  __shared__ __align__(16) short st[16*264];
  __shared__ __align__(16) short gbuf[2][16*776];
  __shared__ float bh[NG];

  for (int i=tid;i<NG;i+=256) bh[i] = b_hh1[i];
  if (tc == 0){
    for (int i=tid;i<16*264;i+=256) st[i] = 0;
  } else {
    for (int i=tid;i<16*256;i+=256)
      st[(i>>8)*264 + (i&255)] = h1g[(size_t)(b0 + (i>>8))*HD + (i&255)];
  }

  bh8 W[12][8];
  const bh8* pt = (const bh8*)pack;
#pragma unroll
  for (int g=0;g<3;++g)
#pragma unroll
    for (int c=0;c<4;++c)
#pragma unroll
      for (int kt=0;kt<8;++kt)
        W[g*4+c][kt] = pt[(size_t)(768 + (g*16 + wid*4 + c)*8 + kt)*64 + lane];

  int mylens[4];
#pragma unroll
  for (int r=0;r<4;++r) mylens[r] = lens[b0 + lq*4 + r];

  {
    bh8 sreg[6];
#pragma unroll
    for (int j=0;j<6;++j){
      int q = tid + j*256;
      sreg[j] = *(const bh8*)(gi1c + ((size_t)0*BTOT + b0)*NG + q*8);
    }
#pragma unroll
    for (int j=0;j<6;++j){
      int q = tid + j*256, row = q/96, col8 = (q%96)*8;
      *(bh8*)(&gbuf[0][row*776 + col8]) = sreg[j];
    }
  }
  __syncthreads();

  const f4 zf = {0.f,0.f,0.f,0.f};
  const short* sp = &st[l15*264 + lq*8];

#pragma unroll 1
  for (int t=0; t<Tc; ++t){
    const int tg = tc*Tc + t;
    const bool more = (t+1 < Tc);
    bh8 nreg[6];
    if (more){
#pragma unroll
      for (int j=0;j<6;++j){
        int q = tid + j*256;
        nreg[j] = *(const bh8*)(gi1c + ((size_t)(t+1)*BTOT + b0)*NG + q*8);
      }
    }
    f4 acc[12];
#pragma unroll
    for (int i=0;i<12;++i) acc[i] = zf;
#pragma unroll
    for (int kt=0;kt<8;++kt){
      bh8 a = *(const bh8*)(sp + kt*32);
#pragma unroll
      for (int i=0;i<12;++i) acc[i] = mfma16(a, W[i][kt], acc[i]);
    }
    __syncthreads();
    const short* gb = gbuf[t&1];
#pragma unroll
    for (int c=0;c<4;++c){
      const int jh = wid*64 + c*16 + l15;
      const float bhr = bh[jh], bhz = bh[256+jh], bhn = bh[512+jh];
#pragma unroll
      for (int r4=0;r4<4;++r4){
        const int row = lq*4 + r4;
        const float gr = bf2f(gb[row*776 + jh]);
        const float gz = bf2f(gb[row*776 + 256 + jh]);
        const float gn = bf2f(gb[row*776 + 512 + jh]);
        const float rg = sigm(acc[c][r4]   + bhr + gr);
        const float zg = sigm(acc[4+c][r4] + bhz + gz);
        const float ng = tanh_f(gn + rg*(acc[8+c][r4] + bhn));
        const float ho = bf2f(st[row*264 + jh]);
        const float h  = ng + zg*(ho - ng);
        st[row*264 + jh] = f2bf(h);
        if (tg == mylens[r4]) outbuf[(size_t)(b0 + row)*HD + jh] = h;
      }
    }
    if (more){
      short* wb = gbuf[(t+1)&1];
#pragma unroll
      for (int j=0;j<6;++j){
        int q = tid + j*256, row = q/96, col8 = (q%96)*8;
        *(bh8*)(&wb[row*776 + col8]) = nreg[j];
      }
    }
    __syncthreads();
  }
  for (int i=tid;i<16*256;i+=256)
    h1g[(size_t)(b0 + (i>>8))*HD + (i&255)] = st[(i>>8)*264 + (i&255)];
}

// ---------------- phase D: head (verified round-3 code, fed from outbuf) ----------------
__global__ __launch_bounds__(512, 1)
void head_kernel(const float* __restrict__ outbuf, const short* __restrict__ pack,
                 const float* __restrict__ b1, const float* __restrict__ b2,
                 float* __restrict__ out)
{
  const int tid = threadIdx.x;
  const int wid = tid >> 6;
  const int lane = tid & 63;
  const int l15 = lane & 15, lq = lane >> 4;
  const int b0 = blockIdx.x * 32;

  __shared__ __align__(16) short zA[32*264];
  __shared__ __align__(16) short zB[32*264];
  __shared__ float b1s[HD], b2s[112];
  if (tid < HD)  b1s[tid] = b1[tid];
  if (tid < 112) b2s[tid] = (tid < LOUT) ? b2[tid] : 0.f;

#pragma unroll
  for (int rt=0;rt<2;++rt)
#pragma unroll
    for (int nt=0;nt<2;++nt){
      const int jb = wid*32 + nt*16 + l15;
#pragma unroll
      for (int r4=0;r4<4;++r4){
        const int row = rt*16 + lq*4 + r4;
        zA[row*264 + jb] = f2bf(outbuf[(size_t)(b0 + row)*HD + jb]);
      }
    }
  __syncthreads();

  const f4 zf = {0.f,0.f,0.f,0.f};
  const int afrag = l15*264 + lq*8;
  constexpr int RT1 = 16*264;
  const bh8* packW1 = (const bh8*)pack + (size_t)(1152 + wid*16)*64 + lane;
  const bh8* packW2 = (const bh8*)pack + (size_t)(1280 + wid*8 )*64 + lane;

  {
    f4 az[2][2]; az[0][0]=zf; az[0][1]=zf; az[1][0]=zf; az[1][1]=zf;
#pragma unroll
    for (int kt=0;kt<8;++kt){
      bh8 a0 = *(const bh8*)(&zA[afrag + kt*32]);
      bh8 a1 = *(const bh8*)(&zA[afrag + RT1 + kt*32]);
#pragma unroll
      for (int nt=0;nt<2;++nt){
        bh8 b = packW1[(nt*8+kt)*64];
        az[nt][0] = mfma16(a0, b, az[nt][0]);
        az[nt][1] = mfma16(a1, b, az[nt][1]);
      }
    }
#pragma unroll
    for (int rt=0;rt<2;++rt)
#pragma unroll
      for (int nt=0;nt<2;++nt){
        const int jb = wid*32 + nt*16 + l15;
#pragma unroll
        for (int r4=0;r4<4;++r4){
          float v = az[nt][rt][r4] + b1s[jb];
          v = (v >= 0.f) ? v : 0.01f*v;     // LeakyReLU
          zB[(rt*16+lq*4+r4)*264 + jb] = f2bf(v);
        }
      }
  }
  __syncthreads();

  if (wid < 7){
    f4 acc2[2]; acc2[0]=zf; acc2[1]=zf;
#pragma unroll
    for (int kt=0;kt<8;++kt){
      bh8 a0 = *(const bh8*)(&zB[afrag + kt*32]);
      bh8 a1 = *(const bh8*)(&zB[afrag + RT1 + kt*32]);
      bh8 b = packW2[kt*64];
      acc2[0] = mfma16(a0, b, acc2[0]);
      acc2[1] = mfma16(a1, b, acc2[1]);
    }
    const int n2 = wid*16 + l15;
    if (n2 < LOUT){
#pragma unroll
      for (int rt=0;rt<2;++rt)
#pragma unroll
        for (int r4=0;r4<4;++r4)
          out[(size_t)(b0 + rt*16 + lq*4 + r4)*LOUT + n2] = acc2[rt][r4] + b2s[n2];
    }
  }
}

extern "C" void kernel_launch(void* const* d_in, const int* in_sizes, int n_in,
                              void* d_out, int out_size, void* d_ws, size_t ws_size,
                              hipStream_t stream)
{
  const int*   tokens = (const int*)  d_in[0];
  const int*   lens   = (const int*)  d_in[1];
  const float* emb    = (const float*)d_in[2];
  const float* w_ih0  = (const float*)d_in[3];
  const float* w_hh0  = (const float*)d_in[4];
  const float* b_ih0  = (const float*)d_in[5];
  const float* b_hh0  = (const float*)d_in[6];
  const float* w_ih1  = (const float*)d_in[7];
  const float* w_hh1  = (const float*)d_in[8];
  const float* b_ih1  = (const float*)d_in[9];
  const float* b_hh1  = (const float*)d_in[10];
  const float* w1     = (const float*)d_in[11];
  const float* b1     = (const float*)d_in[12];
  const float* w2     = (const float*)d_in[13];
  const float* b2     = (const float*)d_in[14];

  char* ws = (char*)d_ws;
  size_t off = 0;
  short* pack = (short*)(ws + off); off += (size_t)1336*1024;       // 1.34 MB
  short* E0h  = (short*)(ws + off); off += (size_t)64*NG*2;         // 96 KB
  short* h0g  = (short*)(ws + off); off += (size_t)BTOT*HD*2;       // 1 MB
  short* h1g  = (short*)(ws + off); off += (size_t)BTOT*HD*2;       // 1 MB
  float* outb = (float*)(ws + off); off += (size_t)BTOT*HD*4;       // 2 MB
  const size_t fixed = off;
  const size_t perT = (size_t)BTOT*HD*2 + (size_t)BTOT*NG*2;        // 4 MB / step
  int Tc = T_STEPS;
  while (Tc > 1 && fixed + (size_t)Tc*perT > ws_size) Tc >>= 1;
  short* s0c  = (short*)(ws + fixed);
  short* gi1c = (short*)(ws + fixed + (size_t)Tc*BTOT*HD*2);

  e0h_kernel <<<(64*NG + 255)/256,   256, 0, stream>>>(emb, w_ih0, b_ih0, E0h);
  pack_kernel<<<(1336*64 + 255)/256, 256, 0, stream>>>(w_hh0, w_ih1, w_hh1, w1, w2, pack);

  const int nch = T_STEPS / Tc;
  for (int tc = 0; tc < nch; ++tc){
    layer0_scan<<<BTOT/16, 256, 0, stream>>>(tokens, E0h, pack, b_hh0, s0c, h0g, tc, Tc);
    gi1_gemm   <<<256,     256, 0, stream>>>(s0c, pack, b_ih1, gi1c, Tc*BTOT/16);
    layer1_scan<<<BTOT/16, 256, 0, stream>>>(lens, gi1c, pack, b_hh1, h1g, outb, tc, Tc);
  }
  head_kernel<<<BTOT/32, 512, 0, stream>>>(outb, pack, b1, b2, (float*)d_out);
}

// Round 6
// 1089.799 us; speedup vs baseline: 4.9927x; 1.4191x over previous
//
#include <hip/hip_runtime.h>
#include <hip/hip_bf16.h>

typedef __attribute__((ext_vector_type(8))) short bh8;   // 8 x bf16 (4 VGPRs)
typedef __attribute__((ext_vector_type(4))) float f4;    // MFMA accumulator

static constexpr int T_STEPS = 128;
static constexpr int BTOT    = 2048;
static constexpr int HD      = 256;
static constexpr int NG      = 768;   // 3*H
static constexpr int LOUT    = 100;

__device__ __forceinline__ short f2bf(float f){
  unsigned u = __builtin_bit_cast(unsigned, f);
  unsigned r = (u + 0x7FFFu + ((u >> 16) & 1u)) >> 16;   // RNE
  return (short)(unsigned short)r;
}
__device__ __forceinline__ float bf2f(short s){
  unsigned u = ((unsigned)(unsigned short)s) << 16;
  return __builtin_bit_cast(float, u);
}
__device__ __forceinline__ f4 mfma16(bh8 a, bh8 b, f4 c){
  return __builtin_amdgcn_mfma_f32_16x16x32_bf16(a, b, c, 0, 0, 0);
}
__device__ __forceinline__ float sigm(float x){
  return __builtin_amdgcn_rcpf(1.f + __expf(-x));
}
__device__ __forceinline__ float tanh_f(float x){
  return 1.f - 2.f*__builtin_amdgcn_rcpf(1.f + __expf(2.f*x));
}

// ---- prep: E0h = bf16(emb @ w_ih0^T + b_ih0 + b_hh0(r,z only))  ([64][768]) ----
// b_hh0 for r,z gates folds in (added outside r*); n-gate's b_hh0 stays separate.
__global__ void e0h_kernel(const float* __restrict__ emb, const float* __restrict__ w_ih0,
                           const float* __restrict__ b_ih0, const float* __restrict__ b_hh0,
                           short* __restrict__ E0h)
{
  int tid = blockIdx.x*blockDim.x + threadIdx.x;
  if (tid >= 64*NG) return;
  int v = tid / NG, n = tid % NG;
  const float4* er = (const float4*)(emb + (size_t)v*HD);
  const float4* wr = (const float4*)(w_ih0 + (size_t)n*HD);
  float s = 0.f;
#pragma unroll 4
  for (int k=0;k<HD/4;++k){
    float4 a = er[k], b = wr[k];
    s += a.x*b.x + a.y*b.y + a.z*b.z + a.w*b.w;
  }
  s += b_ih0[n];
  if (n < 512) s += b_hh0[n];
  E0h[tid] = f2bf(s);
}

// ---- prep: pack weights into fragment-linear bf16 tiles (verified r1-5) ----
// tile = 1KB: value[lane][e] = W[n=ct*16+(lane&15)][k=kt*32+(lane>>4)*8+e]
// tiles 0..383: w_hh0 [ct48][kt8]; 384..767: w_ih1; 768..1151: w_hh1
// 1152..1279: w1 [wid8][nt2][kt8]; 1280..1335: w2 [ntt7][kt8] (N pad 100->112)
__global__ void pack_kernel(const float* __restrict__ w_hh0, const float* __restrict__ w_ih1,
                            const float* __restrict__ w_hh1, const float* __restrict__ w1,
                            const float* __restrict__ w2, short* __restrict__ pack)
{
  int tid = blockIdx.x*blockDim.x + threadIdx.x;
  if (tid >= 1336*64) return;
  int t = tid >> 6, lane = tid & 63;
  int l15 = lane & 15, lq = lane >> 4;
  const float* src = nullptr;
  bool zero = false;
  if (t < 1152){
    int m = t/384, tt = t%384, ct = tt/8, kt = tt%8;
    int n = ct*16 + l15;
    const float* Wm = (m==0) ? w_hh0 : (m==1 ? w_ih1 : w_hh1);
    src = Wm + (size_t)n*HD + kt*32 + lq*8;
  } else if (t < 1280){
    int tt = t - 1152, w = tt/16, rem = tt%16, ntt = rem/8, kt = rem%8;
    int n = w*32 + ntt*16 + l15;
    src = w1 + (size_t)n*HD + kt*32 + lq*8;
  } else {
    int tt = t - 1280, ntt = tt/8, kt = tt%8;
    int n = ntt*16 + l15;
    if (n < LOUT) src = w2 + (size_t)n*HD + kt*32 + lq*8;
    else zero = true;
  }
  bh8 o;
#pragma unroll
  for (int e=0;e<8;++e) o[e] = zero ? (short)0 : f2bf(src[e]);
  ((bh8*)pack)[tid] = o;
}

// ---- phase A: layer-0 scan. 128 wgs x 512 thr (8 waves, 2/SIMD). M=16 rows. ----
// Wave owns 32 h-cols: tiles ct = g*16 + wid*2 + c (g=gate, c=0..1). W = 192 VGPR.
// One barrier/step (st dbuf), h in f32 regs, E0 staged via reg->LDS dbuf.
__global__ __launch_bounds__(512, 1)
void layer0_scan(const int* __restrict__ tokens, const short* __restrict__ E0h,
                 const short* __restrict__ pack, const float* __restrict__ b_hh0,
                 short* __restrict__ s0c, short* __restrict__ h0g, int tc, int Tc)
{
  const int tid = threadIdx.x;
  const int wid = tid >> 6;
  const int lane = tid & 63;
  const int l15 = lane & 15, lq = lane >> 4;
  const int b0 = blockIdx.x * 16;

  __shared__ __align__(16) short st[2][16*264];     // state (bf16), dbuf
  __shared__ __align__(16) short ebuf[2][16*776];   // E0 rows staged, dbuf

  // register-resident weight slice: 3 gates x 2 col-chunks x 8 kt
  bh8 W[3][2][8];
  {
    const bh8* pt = (const bh8*)pack;
#pragma unroll
    for (int g=0;g<3;++g)
#pragma unroll
      for (int c=0;c<2;++c)
#pragma unroll
        for (int kt=0;kt<8;++kt)
          W[g][c][kt] = pt[(size_t)((g*16 + wid*2 + c)*8 + kt)*64 + lane];
  }
  float bhn0[2];
#pragma unroll
  for (int c=0;c<2;++c) bhn0[c] = b_hh0[512 + wid*32 + c*16 + l15];

  float h0s[2][4];
  if (tc == 0){
#pragma unroll
    for (int c=0;c<2;++c)
#pragma unroll
      for (int r=0;r<4;++r) h0s[c][r] = 0.f;
    for (int i=tid;i<16*264;i+=512) st[0][i] = 0;
  } else {
#pragma unroll
    for (int c=0;c<2;++c)
#pragma unroll
      for (int r=0;r<4;++r)
        h0s[c][r] = bf2f(h0g[(size_t)(b0 + lq*4 + r)*HD + wid*32 + c*16 + l15]);
    for (int i=tid;i<16*256;i+=512)
      st[0][(i>>8)*264 + (i&255)] = h0g[(size_t)(b0 + (i>>8))*HD + (i&255)];
  }

  // prologue: stage E0 rows for local t=0
  {
    const int tg0 = tc*Tc;
#pragma unroll
    for (int j=0;j<3;++j){
      int q = tid + j*512, row = q/96, col8 = (q%96)*8;
      int tok = tokens[(size_t)tg0*BTOT + b0 + row];
      bh8 v = *(const bh8*)(E0h + (size_t)tok*NG + col8);
      *(bh8*)(&ebuf[0][row*776 + col8]) = v;
    }
  }
  __syncthreads();

  const f4 zf = {0.f,0.f,0.f,0.f};
  const int crow = tid >> 5, ccol8 = (tid & 31)*8;   // copy-out mapping

#pragma unroll 1
  for (int t=0; t<Tc; ++t){
    const int p = t & 1;
    const int tg = tc*Tc + t;
    const bool more = (t+1 < Tc);
    // issue next-step staging loads (global, latency hidden under MFMA+epilogue)
    bh8 nreg[3];
    if (more){
#pragma unroll
      for (int j=0;j<3;++j){
        int q = tid + j*512, row = q/96, col8 = (q%96)*8;
        int tok = tokens[(size_t)(tg+1)*BTOT + b0 + row];
        nreg[j] = *(const bh8*)(E0h + (size_t)tok*NG + col8);
      }
    }
    // GEMM: gh0 = h0 @ w_hh0^T (48 MFMAs, zero loads)
    f4 acc[3][2];
#pragma unroll
    for (int g=0;g<3;++g){ acc[g][0]=zf; acc[g][1]=zf; }
    {
      const short* sp = &st[p][l15*264 + lq*8];
#pragma unroll
      for (int kt=0;kt<8;++kt){
        bh8 a = *(const bh8*)(sp + kt*32);
#pragma unroll
        for (int g=0;g<3;++g){
          acc[g][0] = mfma16(a, W[g][0][kt], acc[g][0]);
          acc[g][1] = mfma16(a, W[g][1][kt], acc[g][1]);
        }
      }
    }
    // vectorized copy-out of s0_{t-1} (st[p] holds it; both accesses read-only)
    if (t > 0){
      bh8 cv = *(const bh8*)(&st[p][crow*264 + ccol8]);
      *(bh8*)(s0c + ((size_t)(t-1)*BTOT + b0 + crow)*HD + ccol8) = cv;
    }
    // epilogue -> st[p^1] + f32 reg carry
    {
      const short* eb = ebuf[p];
      short* stw = st[p^1];
#pragma unroll
      for (int c=0;c<2;++c){
        const int jh = wid*32 + c*16 + l15;
#pragma unroll
        for (int r4=0;r4<4;++r4){
          const int row = lq*4 + r4;
          const float er = bf2f(eb[row*776 + jh]);
          const float ez = bf2f(eb[row*776 + 256 + jh]);
          const float en = bf2f(eb[row*776 + 512 + jh]);
          const float rg = sigm(acc[0][c][r4] + er);
          const float zg = sigm(acc[1][c][r4] + ez);
          const float ng = tanh_f(en + rg*(acc[2][c][r4] + bhn0[c]));
          const float h = ng + zg*(h0s[c][r4] - ng);
          h0s[c][r4] = h;
          stw[row*264 + jh] = f2bf(h);
        }
      }
    }
    // stage writes for t+1
    if (more){
#pragma unroll
      for (int j=0;j<3;++j){
        int q = tid + j*512, row = q/96, col8 = (q%96)*8;
        *(bh8*)(&ebuf[p^1][row*776 + col8]) = nreg[j];
      }
    }
    __syncthreads();
  }
  // tail: final state -> s0c[Tc-1] and h0g
  {
    bh8 v = *(const bh8*)(&st[Tc & 1][crow*264 + ccol8]);
    *(bh8*)(s0c + ((size_t)(Tc-1)*BTOT + b0 + crow)*HD + ccol8) = v;
    *(bh8*)(h0g + ((size_t)(b0 + crow))*HD + ccol8) = v;
  }
}

// ---- phase B: gi1 = s0 @ w_ih1^T + (b_ih1 + b_hh1(r,z)) (parallel GEMM) ----
__global__ __launch_bounds__(256, 1)
void gi1_gemm(const short* __restrict__ s0c, const short* __restrict__ pack,
              const float* __restrict__ b_ih1, const float* __restrict__ b_hh1,
              short* __restrict__ gi1c, int NC)
{
  const int tid = threadIdx.x;
  const int wid = tid >> 6;
  const int lane = tid & 63;
  const int l15 = lane & 15, lq = lane >> 4;

  __shared__ __align__(16) short ab[2][16*264];
  __shared__ float bi[NG];
  for (int i=tid;i<NG;i+=256) bi[i] = b_ih1[i] + ((i < 512) ? b_hh1[i] : 0.f);

  bh8 W[12][8];
#pragma unroll
  for (int i=0;i<12;++i)
#pragma unroll
    for (int kt=0;kt<8;++kt)
      W[i][kt] = ((const bh8*)pack)[(size_t)(384 + (wid*12+i)*8 + kt)*64 + lane];

  int ci = blockIdx.x;
  if (ci >= NC) return;
  bh8 sr[2];
#pragma unroll
  for (int j=0;j<2;++j){
    int q = tid + j*256;
    sr[j] = *(const bh8*)(s0c + (size_t)ci*4096 + q*8);
  }
#pragma unroll
  for (int j=0;j<2;++j){
    int q = tid + j*256, row = q>>5, col8 = (q&31)*8;
    *(bh8*)(&ab[0][row*264 + col8]) = sr[j];
  }
  __syncthreads();

  const f4 zf = {0.f,0.f,0.f,0.f};
  int p = 0;
#pragma unroll 1
  for (; ci < NC; ci += gridDim.x){
    const int cin = ci + (int)gridDim.x;
    const bool more = (cin < NC);
    if (more){
#pragma unroll
      for (int j=0;j<2;++j){
        int q = tid + j*256;
        sr[j] = *(const bh8*)(s0c + (size_t)cin*4096 + q*8);
      }
    }
    f4 acc[12];
#pragma unroll
    for (int i=0;i<12;++i) acc[i] = zf;
    const short* sp = &ab[p][l15*264 + lq*8];
#pragma unroll
    for (int kt=0;kt<8;++kt){
      bh8 a = *(const bh8*)(sp + kt*32);
#pragma unroll
      for (int i=0;i<12;++i) acc[i] = mfma16(a, W[i][kt], acc[i]);
    }
#pragma unroll
    for (int i=0;i<12;++i){
      const int gc = (wid*12+i)*16 + l15;
      const float b = bi[gc];
#pragma unroll
      for (int r4=0;r4<4;++r4)
        gi1c[(size_t)(ci*16 + lq*4 + r4)*NG + gc] = f2bf(acc[i][r4] + b);
    }
    if (more){
#pragma unroll
      for (int j=0;j<2;++j){
        int q = tid + j*256, row = q>>5, col8 = (q&31)*8;
        *(bh8*)(&ab[p^1][row*264 + col8]) = sr[j];
      }
    }
    p ^= 1;
    __syncthreads();
  }
}

// ---- phase C: layer-1 scan, same slim structure; captures out_t at t==lens ----
__global__ __launch_bounds__(512, 1)
void layer1_scan(const int* __restrict__ lens, const short* __restrict__ gi1c,
                 const short* __restrict__ pack, const float* __restrict__ b_hh1,
                 short* __restrict__ h1g, float* __restrict__ outbuf, int tc, int Tc)
{
  const int tid = threadIdx.x;
  const int wid = tid >> 6;
  const int lane = tid & 63;
  const int l15 = lane & 15, lq = lane >> 4;
  const int b0 = blockIdx.x * 16;

  __shared__ __align__(16) short st[2][16*264];
  __shared__ __align__(16) short gbuf[2][16*776];

  bh8 W[3][2][8];
  {
    const bh8* pt = (const bh8*)pack;
#pragma unroll
    for (int g=0;g<3;++g)
#pragma unroll
      for (int c=0;c<2;++c)
#pragma unroll
        for (int kt=0;kt<8;++kt)
          W[g][c][kt] = pt[(size_t)(768 + (g*16 + wid*2 + c)*8 + kt)*64 + lane];
  }
  float bhn1[2];
#pragma unroll
  for (int c=0;c<2;++c) bhn1[c] = b_hh1[512 + wid*32 + c*16 + l15];

  int mylens[4];
#pragma unroll
  for (int r=0;r<4;++r) mylens[r] = lens[b0 + lq*4 + r];

  float h1s[2][4];
  if (tc == 0){
#pragma unroll
    for (int c=0;c<2;++c)
#pragma unroll
      for (int r=0;r<4;++r) h1s[c][r] = 0.f;
    for (int i=tid;i<16*264;i+=512) st[0][i] = 0;
  } else {
#pragma unroll
    for (int c=0;c<2;++c)
#pragma unroll
      for (int r=0;r<4;++r)
        h1s[c][r] = bf2f(h1g[(size_t)(b0 + lq*4 + r)*HD + wid*32 + c*16 + l15]);
    for (int i=tid;i<16*256;i+=512)
      st[0][(i>>8)*264 + (i&255)] = h1g[(size_t)(b0 + (i>>8))*HD + (i&255)];
  }

  {
#pragma unroll
    for (int j=0;j<3;++j){
      int q = tid + j*512, row = q/96, col8 = (q%96)*8;
      bh8 v = *(const bh8*)(gi1c + ((size_t)0*BTOT + b0 + row)*NG + col8);
      *(bh8*)(&gbuf[0][row*776 + col8]) = v;
    }
  }
  __syncthreads();

  const f4 zf = {0.f,0.f,0.f,0.f};
  const int crow = tid >> 5, ccol8 = (tid & 31)*8;

#pragma unroll 1
  for (int t=0; t<Tc; ++t){
    const int p = t & 1;
    const int tg = tc*Tc + t;
    const bool more = (t+1 < Tc);
    bh8 nreg[3];
    if (more){
#pragma unroll
      for (int j=0;j<3;++j){
        int q = tid + j*512, row = q/96, col8 = (q%96)*8;
        nreg[j] = *(const bh8*)(gi1c + ((size_t)(t+1)*BTOT + b0 + row)*NG + col8);
      }
    }
    f4 acc[3][2];
#pragma unroll
    for (int g=0;g<3;++g){ acc[g][0]=zf; acc[g][1]=zf; }
    {
      const short* sp = &st[p][l15*264 + lq*8];
#pragma unroll
      for (int kt=0;kt<8;++kt){
        bh8 a = *(const bh8*)(sp + kt*32);
#pragma unroll
        for (int g=0;g<3;++g){
          acc[g][0] = mfma16(a, W[g][0][kt], acc[g][0]);
          acc[g][1] = mfma16(a, W[g][1][kt], acc[g][1]);
        }
      }
    }
    {
      const short* gb = gbuf[p];
      short* stw = st[p^1];
#pragma unroll
      for (int c=0;c<2;++c){
        const int jh = wid*32 + c*16 + l15;
#pragma unroll
        for (int r4=0;r4<4;++r4){
          const int row = lq*4 + r4;
          const float gr = bf2f(gb[row*776 + jh]);
          const float gz = bf2f(gb[row*776 + 256 + jh]);
          const float gn = bf2f(gb[row*776 + 512 + jh]);
          const float rg = sigm(acc[0][c][r4] + gr);
          const float zg = sigm(acc[1][c][r4] + gz);
          const float ng = tanh_f(gn + rg*(acc[2][c][r4] + bhn1[c]));
          const float h = ng + zg*(h1s[c][r4] - ng);
          h1s[c][r4] = h;
          if (tg == mylens[r4]) outbuf[(size_t)(b0 + row)*HD + jh] = h;
          stw[row*264 + jh] = f2bf(h);
        }
      }
    }
    if (more){
#pragma unroll
      for (int j=0;j<3;++j){
        int q = tid + j*512, row = q/96, col8 = (q%96)*8;
        *(bh8*)(&gbuf[p^1][row*776 + col8]) = nreg[j];
      }
    }
    __syncthreads();
  }
  {
    bh8 v = *(const bh8*)(&st[Tc & 1][crow*264 + ccol8]);
    *(bh8*)(h1g + ((size_t)(b0 + crow))*HD + ccol8) = v;
  }
}

// ---- phase D: head (verified r1-5), fed from outbuf ----
__global__ __launch_bounds__(512, 1)
void head_kernel(const float* __restrict__ outbuf, const short* __restrict__ pack,
                 const float* __restrict__ b1, const float* __restrict__ b2,
                 float* __restrict__ out)
{
  const int tid = threadIdx.x;
  const int wid = tid >> 6;
  const int lane = tid & 63;
  const int l15 = lane & 15, lq = lane >> 4;
  const int b0 = blockIdx.x * 32;

  __shared__ __align__(16) short zA[32*264];
  __shared__ __align__(16) short zB[32*264];
  __shared__ float b1s[HD], b2s[112];
  if (tid < HD)  b1s[tid] = b1[tid];
  if (tid < 112) b2s[tid] = (tid < LOUT) ? b2[tid] : 0.f;

#pragma unroll
  for (int rt=0;rt<2;++rt)
#pragma unroll
    for (int nt=0;nt<2;++nt){
      const int jb = wid*32 + nt*16 + l15;
#pragma unroll
      for (int r4=0;r4<4;++r4){
        const int row = rt*16 + lq*4 + r4;
        zA[row*264 + jb] = f2bf(outbuf[(size_t)(b0 + row)*HD + jb]);
      }
    }
  __syncthreads();

  const f4 zf = {0.f,0.f,0.f,0.f};
  const int afrag = l15*264 + lq*8;
  constexpr int RT1 = 16*264;
  const bh8* packW1 = (const bh8*)pack + (size_t)(1152 + wid*16)*64 + lane;
  const bh8* packW2 = (const bh8*)pack + (size_t)(1280 + wid*8 )*64 + lane;

  {
    f4 az[2][2]; az[0][0]=zf; az[0][1]=zf; az[1][0]=zf; az[1][1]=zf;
#pragma unroll
    for (int kt=0;kt<8;++kt){
      bh8 a0 = *(const bh8*)(&zA[afrag + kt*32]);
      bh8 a1 = *(const bh8*)(&zA[afrag + RT1 + kt*32]);
#pragma unroll
      for (int nt=0;nt<2;++nt){
        bh8 b = packW1[(nt*8+kt)*64];
        az[nt][0] = mfma16(a0, b, az[nt][0]);
        az[nt][1] = mfma16(a1, b, az[nt][1]);
      }
    }
#pragma unroll
    for (int rt=0;rt<2;++rt)
#pragma unroll
      for (int nt=0;nt<2;++nt){
        const int jb = wid*32 + nt*16 + l15;
#pragma unroll
        for (int r4=0;r4<4;++r4){
          float v = az[nt][rt][r4] + b1s[jb];
          v = (v >= 0.f) ? v : 0.01f*v;     // LeakyReLU
          zB[(rt*16+lq*4+r4)*264 + jb] = f2bf(v);
        }
      }
  }
  __syncthreads();

  if (wid < 7){
    f4 acc2[2]; acc2[0]=zf; acc2[1]=zf;
#pragma unroll
    for (int kt=0;kt<8;++kt){
      bh8 a0 = *(const bh8*)(&zB[afrag + kt*32]);
      bh8 a1 = *(const bh8*)(&zB[afrag + RT1 + kt*32]);
      bh8 b = packW2[kt*64];
      acc2[0] = mfma16(a0, b, acc2[0]);
      acc2[1] = mfma16(a1, b, acc2[1]);
    }
    const int n2 = wid*16 + l15;
    if (n2 < LOUT){
#pragma unroll
      for (int rt=0;rt<2;++rt)
#pragma unroll
        for (int r4=0;r4<4;++r4)
          out[(size_t)(b0 + rt*16 + lq*4 + r4)*LOUT + n2] = acc2[rt][r4] + b2s[n2];
    }
  }
}

extern "C" void kernel_launch(void* const* d_in, const int* in_sizes, int n_in,
                              void* d_out, int out_size, void* d_ws, size_t ws_size,
                              hipStream_t stream)
{
  const int*   tokens = (const int*)  d_in[0];
  const int*   lens   = (const int*)  d_in[1];
  const float* emb    = (const float*)d_in[2];
  const float* w_ih0  = (const float*)d_in[3];
  const float* w_hh0  = (const float*)d_in[4];
  const float* b_ih0  = (const float*)d_in[5];
  const float* b_hh0  = (const float*)d_in[6];
  const float* w_ih1  = (const float*)d_in[7];
  const float* w_hh1  = (const float*)d_in[8];
  const float* b_ih1  = (const float*)d_in[9];
  const float* b_hh1  = (const float*)d_in[10];
  const float* w1     = (const float*)d_in[11];
  const float* b1     = (const float*)d_in[12];
  const float* w2     = (const float*)d_in[13];
  const float* b2     = (const float*)d_in[14];

  char* ws = (char*)d_ws;
  size_t off = 0;
  short* pack = (short*)(ws + off); off += (size_t)1336*1024;       // 1.34 MB
  short* E0h  = (short*)(ws + off); off += (size_t)64*NG*2;         // 96 KB
  short* h0g  = (short*)(ws + off); off += (size_t)BTOT*HD*2;       // 1 MB
  short* h1g  = (short*)(ws + off); off += (size_t)BTOT*HD*2;       // 1 MB
  float* outb = (float*)(ws + off); off += (size_t)BTOT*HD*4;       // 2 MB
  const size_t fixed = off;
  const size_t perT = (size_t)BTOT*HD*2 + (size_t)BTOT*NG*2;        // 4 MB / step
  int Tc = T_STEPS;
  while (Tc > 1 && fixed + (size_t)Tc*perT > ws_size) Tc >>= 1;
  short* s0c  = (short*)(ws + fixed);
  short* gi1c = (short*)(ws + fixed + (size_t)Tc*BTOT*HD*2);

  e0h_kernel <<<(64*NG + 255)/256,   256, 0, stream>>>(emb, w_ih0, b_ih0, b_hh0, E0h);
  pack_kernel<<<(1336*64 + 255)/256, 256, 0, stream>>>(w_hh0, w_ih1, w_hh1, w1, w2, pack);

  const int nch = T_STEPS / Tc;
  for (int tc = 0; tc < nch; ++tc){
    layer0_scan<<<BTOT/16, 512, 0, stream>>>(tokens, E0h, pack, b_hh0, s0c, h0g, tc, Tc);
    gi1_gemm   <<<256,     256, 0, stream>>>(s0c, pack, b_ih1, b_hh1, gi1c, Tc*BTOT/16);
    layer1_scan<<<BTOT/16, 512, 0, stream>>>(lens, gi1c, pack, b_hh1, h1g, outb, tc, Tc);
  }
  head_kernel<<<BTOT/32, 512, 0, stream>>>(outb, pack, b1, b2, (float*)d_out);
}

// Round 7
// 890.519 us; speedup vs baseline: 6.1100x; 1.2238x over previous
//
#include <hip/hip_runtime.h>
#include <hip/hip_bf16.h>

typedef __attribute__((ext_vector_type(8))) short bh8;   // 8 x bf16 (4 VGPRs)
typedef __attribute__((ext_vector_type(4))) short sh4;   // 4 x bf16
typedef __attribute__((ext_vector_type(4))) float f4;    // MFMA accumulator

static constexpr int T_STEPS = 128;
static constexpr int BTOT    = 2048;
static constexpr int HD      = 256;
static constexpr int NG      = 768;   // 3*H
static constexpr int LOUT    = 100;

__device__ __forceinline__ short f2bf(float f){
  unsigned u = __builtin_bit_cast(unsigned, f);
  unsigned r = (u + 0x7FFFu + ((u >> 16) & 1u)) >> 16;   // RNE
  return (short)(unsigned short)r;
}
__device__ __forceinline__ float bf2f(short s){
  unsigned u = ((unsigned)(unsigned short)s) << 16;
  return __builtin_bit_cast(float, u);
}
__device__ __forceinline__ f4 mfma16(bh8 a, bh8 b, f4 c){
  return __builtin_amdgcn_mfma_f32_16x16x32_bf16(a, b, c, 0, 0, 0);
}
__device__ __forceinline__ float sigm(float x){
  return __builtin_amdgcn_rcpf(1.f + __expf(-x));
}
__device__ __forceinline__ float tanh_f(float x){
  return 1.f - 2.f*__builtin_amdgcn_rcpf(1.f + __expf(2.f*x));
}

// ---- prep: E0g = per-thread-permuted bf16(emb @ w_ih0^T + biases) ----
// layout: [tok(64)][wid(8)][l15(16)][8]  slot g*2+c (slots 6,7 pad)
// r,z slots include b_ih0 + b_hh0; n slot includes b_ih0 only.
__global__ void e0g_kernel(const float* __restrict__ emb, const float* __restrict__ w_ih0,
                           const float* __restrict__ b_ih0, const float* __restrict__ b_hh0,
                           short* __restrict__ E0g)
{
  int tid = blockIdx.x*blockDim.x + threadIdx.x;
  if (tid >= 64*NG) return;
  int v = tid / NG, n = tid % NG;
  const float4* er = (const float4*)(emb + (size_t)v*HD);
  const float4* wr = (const float4*)(w_ih0 + (size_t)n*HD);
  float s = 0.f;
#pragma unroll 4
  for (int k=0;k<HD/4;++k){
    float4 a = er[k], b = wr[k];
    s += a.x*b.x + a.y*b.y + a.z*b.z + a.w*b.w;
  }
  s += b_ih0[n];
  if (n < 512) s += b_hh0[n];
  int g = n >> 8, j = n & 255;
  int wid = j >> 5, c = (j >> 4) & 1, l15 = j & 15;
  E0g[(size_t)v*1024 + wid*128 + l15*8 + g*2 + c] = f2bf(s);
}

// ---- prep: pack weights into fragment-linear bf16 tiles (verified r1-6) ----
__global__ void pack_kernel(const float* __restrict__ w_hh0, const float* __restrict__ w_ih1,
                            const float* __restrict__ w_hh1, const float* __restrict__ w1,
                            const float* __restrict__ w2, short* __restrict__ pack)
{
  int tid = blockIdx.x*blockDim.x + threadIdx.x;
  if (tid >= 1336*64) return;
  int t = tid >> 6, lane = tid & 63;
  int l15 = lane & 15, lq = lane >> 4;
  const float* src = nullptr;
  bool zero = false;
  if (t < 1152){
    int m = t/384, tt = t%384, ct = tt/8, kt = tt%8;
    int n = ct*16 + l15;
    const float* Wm = (m==0) ? w_hh0 : (m==1 ? w_ih1 : w_hh1);
    src = Wm + (size_t)n*HD + kt*32 + lq*8;
  } else if (t < 1280){
    int tt = t - 1152, w = tt/16, rem = tt%16, ntt = rem/8, kt = rem%8;
    int n = w*32 + ntt*16 + l15;
    src = w1 + (size_t)n*HD + kt*32 + lq*8;
  } else {
    int tt = t - 1280, ntt = tt/8, kt = tt%8;
    int n = ntt*16 + l15;
    if (n < LOUT) src = w2 + (size_t)n*HD + kt*32 + lq*8;
    else zero = true;
  }
  bh8 o;
#pragma unroll
  for (int e=0;e<8;++e) o[e] = zero ? (short)0 : f2bf(src[e]);
  ((bh8*)pack)[tid] = o;
}

// ---- phase A: layer-0 scan. No operand LDS round-trip: E0g gathered to regs. ----
__global__ __launch_bounds__(512, 1)
void layer0_scan(const int* __restrict__ tokens, const short* __restrict__ E0g,
                 const short* __restrict__ pack, const float* __restrict__ b_hh0,
                 short* __restrict__ s0c, short* __restrict__ h0g, int tc, int Tc)
{
  const int tid = threadIdx.x;
  const int wid = tid >> 6;
  const int lane = tid & 63;
  const int l15 = lane & 15, lq = lane >> 4;
  const int b0 = blockIdx.x * 16;

  __shared__ __align__(16) short st[2][16*264];   // bf16 state, dbuf

  bh8 W[3][2][8];
  {
    const bh8* pt = (const bh8*)pack;
#pragma unroll
    for (int g=0;g<3;++g)
#pragma unroll
      for (int c=0;c<2;++c)
#pragma unroll
        for (int kt=0;kt<8;++kt)
          W[g][c][kt] = pt[(size_t)((g*16 + wid*2 + c)*8 + kt)*64 + lane];
  }
  float bhn0[2];
#pragma unroll
  for (int c=0;c<2;++c) bhn0[c] = b_hh0[512 + wid*32 + c*16 + l15];

  if (tc == 0){
    for (int i=tid;i<16*264;i+=512) st[0][i] = 0;
  } else {
    for (int i=tid;i<16*256;i+=512)
      st[0][(i>>8)*264 + (i&255)] = h0g[(size_t)(b0 + (i>>8))*HD + (i&255)];
  }

  // prologue: tokens(t=0) -> E0g gather for step 0
  const int e0base = wid*128 + l15*8;
  bh8 ev[4];
  {
    const int tg0 = tc*Tc;
    int tokr[4];
#pragma unroll
    for (int r=0;r<4;++r) tokr[r] = tokens[(size_t)tg0*BTOT + b0 + lq*4 + r];
#pragma unroll
    for (int r=0;r<4;++r)
      ev[r] = *(const bh8*)(E0g + (size_t)tokr[r]*1024 + e0base);
  }
  __syncthreads();

  const f4 zf = {0.f,0.f,0.f,0.f};
  const int crow = tid >> 5, ccol8 = (tid & 31)*8;

#pragma unroll 1
  for (int t=0; t<Tc; ++t){
    const int p = t & 1;
    const int tg = tc*Tc + t;
    // issue next-step token loads (consumed late this step)
    const int tn = (tg+1 < T_STEPS) ? tg+1 : T_STEPS-1;
    int tokn[4];
#pragma unroll
    for (int r=0;r<4;++r) tokn[r] = tokens[(size_t)tn*BTOT + b0 + lq*4 + r];
    // GEMM (zero loads)
    f4 acc[3][2];
#pragma unroll
    for (int g=0;g<3;++g){ acc[g][0]=zf; acc[g][1]=zf; }
    {
      const short* sp = &st[p][l15*264 + lq*8];
#pragma unroll
      for (int kt=0;kt<8;++kt){
        bh8 a = *(const bh8*)(sp + kt*32);
#pragma unroll
        for (int g=0;g<3;++g){
          acc[g][0] = mfma16(a, W[g][0][kt], acc[g][0]);
          acc[g][1] = mfma16(a, W[g][1][kt], acc[g][1]);
        }
      }
    }
    // vectorized copy-out of s0_{t-1}
    if (t > 0){
      bh8 cv = *(const bh8*)(&st[p][crow*264 + ccol8]);
      *(bh8*)(s0c + ((size_t)(t-1)*BTOT + b0 + crow)*HD + ccol8) = cv;
    }
    // epilogue: operands already in regs (ev), h_old read from st[p]
    {
      short* stw = st[p^1];
#pragma unroll
      for (int c=0;c<2;++c){
        const int jh = wid*32 + c*16 + l15;
#pragma unroll
        for (int r4=0;r4<4;++r4){
          const int row = lq*4 + r4;
          const float er = bf2f(ev[r4][c]);
          const float ez = bf2f(ev[r4][2+c]);
          const float en = bf2f(ev[r4][4+c]);
          const float rg = sigm(acc[0][c][r4] + er);
          const float zg = sigm(acc[1][c][r4] + ez);
          const float ng = tanh_f(en + rg*(acc[2][c][r4] + bhn0[c]));
          const float ho = bf2f(st[p][row*264 + jh]);
          const float h = ng + zg*(ho - ng);
          stw[row*264 + jh] = f2bf(h);
        }
      }
    }
    // issue E0g gathers for t+1 (full barrier+MFMA window to return)
#pragma unroll
    for (int r=0;r<4;++r)
      ev[r] = *(const bh8*)(E0g + (size_t)tokn[r]*1024 + e0base);
    __syncthreads();
  }
  // tail: final state -> s0c[Tc-1] and h0g
  {
    bh8 cv = *(const bh8*)(&st[Tc & 1][crow*264 + ccol8]);
    *(bh8*)(s0c + ((size_t)(Tc-1)*BTOT + b0 + crow)*HD + ccol8) = cv;
    *(bh8*)(h0g + ((size_t)(b0 + crow))*HD + ccol8) = cv;
  }
}

// ---- phase B: gi1 = s0 @ w_ih1^T + biases, output in per-thread-permuted layout ----
// gi1p[ci][tidp(512)][g(3)][c(2)][r4(4)] bf16, ci = t*128 + bblk
__global__ __launch_bounds__(256, 1)
void gi1_gemm(const short* __restrict__ s0c, const short* __restrict__ pack,
              const float* __restrict__ b_ih1, const float* __restrict__ b_hh1,
              short* __restrict__ gi1p, int NC)
{
  const int tid = threadIdx.x;
  const int wid = tid >> 6;
  const int lane = tid & 63;
  const int l15 = lane & 15, lq = lane >> 4;

  __shared__ __align__(16) short ab[2][16*264];
  __shared__ float bi[NG];
  for (int i=tid;i<NG;i+=256) bi[i] = b_ih1[i] + ((i < 512) ? b_hh1[i] : 0.f);

  bh8 W[12][8];
#pragma unroll
  for (int i=0;i<12;++i)
#pragma unroll
    for (int kt=0;kt<8;++kt)
      W[i][kt] = ((const bh8*)pack)[(size_t)(384 + (wid*12+i)*8 + kt)*64 + lane];

  int ci = blockIdx.x;
  if (ci >= NC) return;
  bh8 sr[2];
#pragma unroll
  for (int j=0;j<2;++j){
    int q = tid + j*256;
    sr[j] = *(const bh8*)(s0c + (size_t)ci*4096 + q*8);
  }
#pragma unroll
  for (int j=0;j<2;++j){
    int q = tid + j*256, row = q>>5, col8 = (q&31)*8;
    *(bh8*)(&ab[0][row*264 + col8]) = sr[j];
  }
  __syncthreads();

  const f4 zf = {0.f,0.f,0.f,0.f};
  int p = 0;
#pragma unroll 1
  for (; ci < NC; ci += gridDim.x){
    const int cin = ci + (int)gridDim.x;
    const bool more = (cin < NC);
    if (more){
#pragma unroll
      for (int j=0;j<2;++j){
        int q = tid + j*256;
        sr[j] = *(const bh8*)(s0c + (size_t)cin*4096 + q*8);
      }
    }
    f4 acc[12];
#pragma unroll
    for (int i=0;i<12;++i) acc[i] = zf;
    const short* sp = &ab[p][l15*264 + lq*8];
#pragma unroll
    for (int kt=0;kt<8;++kt){
      bh8 a = *(const bh8*)(sp + kt*32);
#pragma unroll
      for (int i=0;i<12;++i) acc[i] = mfma16(a, W[i][kt], acc[i]);
    }
#pragma unroll
    for (int i=0;i<12;++i){
      const int gc = (wid*12+i)*16 + l15;
      const int g = gc >> 8, j = gc & 255;
      const int widp = j >> 5, c = (j >> 4) & 1;
      const int tidp = widp*64 + lq*16 + l15;
      const float b = bi[gc];
      sh4 v;
#pragma unroll
      for (int r4=0;r4<4;++r4) v[r4] = f2bf(acc[i][r4] + b);
      *(sh4*)(gi1p + ((size_t)ci*512 + tidp)*24 + g*8 + c*4) = v;
    }
    if (more){
#pragma unroll
      for (int j=0;j<2;++j){
        int q = tid + j*256, row = q>>5, col8 = (q&31)*8;
        *(bh8*)(&ab[p^1][row*264 + col8]) = sr[j];
      }
    }
    p ^= 1;
    __syncthreads();
  }
}

// ---- phase C: layer-1 scan: gi1p loaded straight to epilogue regs ----
__global__ __launch_bounds__(512, 1)
void layer1_scan(const int* __restrict__ lens, const short* __restrict__ gi1p,
                 const short* __restrict__ pack, const float* __restrict__ b_hh1,
                 short* __restrict__ h1g, short* __restrict__ outbuf, int tc, int Tc)
{
  const int tid = threadIdx.x;
  const int wid = tid >> 6;
  const int lane = tid & 63;
  const int l15 = lane & 15, lq = lane >> 4;
  const int b0 = blockIdx.x * 16;
  const int bblk = blockIdx.x;

  __shared__ __align__(16) short st[2][16*264];

  bh8 W[3][2][8];
  {
    const bh8* pt = (const bh8*)pack;
#pragma unroll
    for (int g=0;g<3;++g)
#pragma unroll
      for (int c=0;c<2;++c)
#pragma unroll
        for (int kt=0;kt<8;++kt)
          W[g][c][kt] = pt[(size_t)(768 + (g*16 + wid*2 + c)*8 + kt)*64 + lane];
  }
  float bhn1[2];
#pragma unroll
  for (int c=0;c<2;++c) bhn1[c] = b_hh1[512 + wid*32 + c*16 + l15];

  int mylens[4];
#pragma unroll
  for (int r=0;r<4;++r) mylens[r] = lens[b0 + lq*4 + r];

  if (tc == 0){
    for (int i=tid;i<16*264;i+=512) st[0][i] = 0;
  } else {
    for (int i=tid;i<16*256;i+=512)
      st[0][(i>>8)*264 + (i&255)] = h1g[(size_t)(b0 + (i>>8))*HD + (i&255)];
  }

  // prologue: gi1 operands for t=0
  bh8 gv[3];
#pragma unroll
  for (int g=0;g<3;++g)
    gv[g] = *(const bh8*)(gi1p + ((size_t)bblk*512 + tid)*24 + g*8);
  __syncthreads();

  const f4 zf = {0.f,0.f,0.f,0.f};
  const int crow = tid >> 5, ccol8 = (tid & 31)*8;

#pragma unroll 1
  for (int t=0; t<Tc; ++t){
    const int p = t & 1;
    const int tg = tc*Tc + t;
    f4 acc[3][2];
#pragma unroll
    for (int g=0;g<3;++g){ acc[g][0]=zf; acc[g][1]=zf; }
    {
      const short* sp = &st[p][l15*264 + lq*8];
#pragma unroll
      for (int kt=0;kt<8;++kt){
        bh8 a = *(const bh8*)(sp + kt*32);
#pragma unroll
        for (int g=0;g<3;++g){
          acc[g][0] = mfma16(a, W[g][0][kt], acc[g][0]);
          acc[g][1] = mfma16(a, W[g][1][kt], acc[g][1]);
        }
      }
    }
    {
      short* stw = st[p^1];
#pragma unroll
      for (int c=0;c<2;++c){
        const int jh = wid*32 + c*16 + l15;
#pragma unroll
        for (int r4=0;r4<4;++r4){
          const int row = lq*4 + r4;
          const float gr = bf2f(gv[0][c*4+r4]);
          const float gz = bf2f(gv[1][c*4+r4]);
          const float gn = bf2f(gv[2][c*4+r4]);
          const float rg = sigm(acc[0][c][r4] + gr);
          const float zg = sigm(acc[1][c][r4] + gz);
          const float ng = tanh_f(gn + rg*(acc[2][c][r4] + bhn1[c]));
          const float ho = bf2f(st[p][row*264 + jh]);
          const float h = ng + zg*(ho - ng);
          const short hb = f2bf(h);
          stw[row*264 + jh] = hb;
          if (tg == mylens[r4]) outbuf[(size_t)(b0 + row)*HD + jh] = hb;
        }
      }
    }
    // issue gi1 operands for t+1 (barrier + next MFMA window)
    if (t+1 < Tc){
#pragma unroll
      for (int g=0;g<3;++g)
        gv[g] = *(const bh8*)(gi1p + (((size_t)(t+1)*128 + bblk)*512 + tid)*24 + g*8);
    }
    __syncthreads();
  }
  {
    bh8 cv = *(const bh8*)(&st[Tc & 1][crow*264 + ccol8]);
    *(bh8*)(h1g + ((size_t)(b0 + crow))*HD + ccol8) = cv;
  }
}

// ---- phase D: head (verified r1-6; outbuf now bf16) ----
__global__ __launch_bounds__(512, 1)
void head_kernel(const short* __restrict__ outbuf, const short* __restrict__ pack,
                 const float* __restrict__ b1, const float* __restrict__ b2,
                 float* __restrict__ out)
{
  const int tid = threadIdx.x;
  const int wid = tid >> 6;
  const int lane = tid & 63;
  const int l15 = lane & 15, lq = lane >> 4;
  const int b0 = blockIdx.x * 32;

  __shared__ __align__(16) short zA[32*264];
  __shared__ __align__(16) short zB[32*264];
  __shared__ float b1s[HD], b2s[112];
  if (tid < HD)  b1s[tid] = b1[tid];
  if (tid < 112) b2s[tid] = (tid < LOUT) ? b2[tid] : 0.f;

  for (int i=tid;i<32*256;i+=512){
    int row = i >> 8, col = i & 255;
    zA[row*264 + col] = outbuf[(size_t)(b0 + row)*HD + col];
  }
  __syncthreads();

  const f4 zf = {0.f,0.f,0.f,0.f};
  const int afrag = l15*264 + lq*8;
  constexpr int RT1 = 16*264;
  const bh8* packW1 = (const bh8*)pack + (size_t)(1152 + wid*16)*64 + lane;
  const bh8* packW2 = (const bh8*)pack + (size_t)(1280 + wid*8 )*64 + lane;

  {
    f4 az[2][2]; az[0][0]=zf; az[0][1]=zf; az[1][0]=zf; az[1][1]=zf;
#pragma unroll
    for (int kt=0;kt<8;++kt){
      bh8 a0 = *(const bh8*)(&zA[afrag + kt*32]);
      bh8 a1 = *(const bh8*)(&zA[afrag + RT1 + kt*32]);
#pragma unroll
      for (int nt=0;nt<2;++nt){
        bh8 b = packW1[(nt*8+kt)*64];
        az[nt][0] = mfma16(a0, b, az[nt][0]);
        az[nt][1] = mfma16(a1, b, az[nt][1]);
      }
    }
#pragma unroll
    for (int rt=0;rt<2;++rt)
#pragma unroll
      for (int nt=0;nt<2;++nt){
        const int jb = wid*32 + nt*16 + l15;
#pragma unroll
        for (int r4=0;r4<4;++r4){
          float v = az[nt][rt][r4] + b1s[jb];
          v = (v >= 0.f) ? v : 0.01f*v;     // LeakyReLU
          zB[(rt*16+lq*4+r4)*264 + jb] = f2bf(v);
        }
      }
  }
  __syncthreads();

  if (wid < 7){
    f4 acc2[2]; acc2[0]=zf; acc2[1]=zf;
#pragma unroll
    for (int kt=0;kt<8;++kt){
      bh8 a0 = *(const bh8*)(&zB[afrag + kt*32]);
      bh8 a1 = *(const bh8*)(&zB[afrag + RT1 + kt*32]);
      bh8 b = packW2[kt*64];
      acc2[0] = mfma16(a0, b, acc2[0]);
      acc2[1] = mfma16(a1, b, acc2[1]);
    }
    const int n2 = wid*16 + l15;
    if (n2 < LOUT){
#pragma unroll
      for (int rt=0;rt<2;++rt)
#pragma unroll
        for (int r4=0;r4<4;++r4)
          out[(size_t)(b0 + rt*16 + lq*4 + r4)*LOUT + n2] = acc2[rt][r4] + b2s[n2];
    }
  }
}

extern "C" void kernel_launch(void* const* d_in, const int* in_sizes, int n_in,
                              void* d_out, int out_size, void* d_ws, size_t ws_size,
                              hipStream_t stream)
{
  const int*   tokens = (const int*)  d_in[0];
  const int*   lens   = (const int*)  d_in[1];
  const float* emb    = (const float*)d_in[2];
  const float* w_ih0  = (const float*)d_in[3];
  const float* w_hh0  = (const float*)d_in[4];
  const float* b_ih0  = (const float*)d_in[5];
  const float* b_hh0  = (const float*)d_in[6];
  const float* w_ih1  = (const float*)d_in[7];
  const float* w_hh1  = (const float*)d_in[8];
  const float* b_ih1  = (const float*)d_in[9];
  const float* b_hh1  = (const float*)d_in[10];
  const float* w1     = (const float*)d_in[11];
  const float* b1     = (const float*)d_in[12];
  const float* w2     = (const float*)d_in[13];
  const float* b2     = (const float*)d_in[14];

  char* ws = (char*)d_ws;
  size_t off = 0;
  short* pack = (short*)(ws + off); off += (size_t)1336*1024;       // 1.34 MB
  short* E0g  = (short*)(ws + off); off += (size_t)64*1024*2;       // 128 KB
  short* h0g  = (short*)(ws + off); off += (size_t)BTOT*HD*2;       // 1 MB
  short* h1g  = (short*)(ws + off); off += (size_t)BTOT*HD*2;       // 1 MB
  short* outb = (short*)(ws + off); off += (size_t)BTOT*HD*2;       // 1 MB
  const size_t fixed = off;
  const size_t perT = (size_t)BTOT*HD*2 + (size_t)BTOT*NG*2;        // 4 MB / step
  int Tc = T_STEPS;
  while (Tc > 1 && fixed + (size_t)Tc*perT > ws_size) Tc >>= 1;
  short* s0c  = (short*)(ws + fixed);
  short* gi1p = (short*)(ws + fixed + (size_t)Tc*BTOT*HD*2);

  e0g_kernel <<<(64*NG + 255)/256,   256, 0, stream>>>(emb, w_ih0, b_ih0, b_hh0, E0g);
  pack_kernel<<<(1336*64 + 255)/256, 256, 0, stream>>>(w_hh0, w_ih1, w_hh1, w1, w2, pack);

  const int nch = T_STEPS / Tc;
  for (int tc = 0; tc < nch; ++tc){
    layer0_scan<<<BTOT/16, 512, 0, stream>>>(tokens, E0g, pack, b_hh0, s0c, h0g, tc, Tc);
    gi1_gemm   <<<256,     256, 0, stream>>>(s0c, pack, b_ih1, b_hh1, gi1p, Tc*BTOT/16);
    layer1_scan<<<BTOT/16, 512, 0, stream>>>(lens, gi1p, pack, b_hh1, h1g, outb, tc, Tc);
  }
  head_kernel<<<BTOT/32, 512, 0, stream>>>(outb, pack, b1, b2, (float*)d_out);
}

// Round 8
// 675.724 us; speedup vs baseline: 8.0522x; 1.3179x over previous
//
#include <hip/hip_runtime.h>
#include <hip/hip_bf16.h>

typedef __attribute__((ext_vector_type(8))) short bh8;   // 8 x bf16 (4 VGPRs)
typedef __attribute__((ext_vector_type(4))) short sh4;   // 4 x bf16
typedef __attribute__((ext_vector_type(4))) float f4;    // MFMA accumulator

static constexpr int T_STEPS = 128;
static constexpr int BTOT    = 2048;
static constexpr int HD      = 256;
static constexpr int NG      = 768;   // 3*H
static constexpr int LOUT    = 100;

__device__ __forceinline__ short f2bf(float f){
  unsigned u = __builtin_bit_cast(unsigned, f);
  unsigned r = (u + 0x7FFFu + ((u >> 16) & 1u)) >> 16;   // RNE
  return (short)(unsigned short)r;
}
__device__ __forceinline__ float bf2f(short s){
  unsigned u = ((unsigned)(unsigned short)s) << 16;
  return __builtin_bit_cast(float, u);
}
__device__ __forceinline__ f4 mfma16(bh8 a, bh8 b, f4 c){
  return __builtin_amdgcn_mfma_f32_16x16x32_bf16(a, b, c, 0, 0, 0);
}
__device__ __forceinline__ float sigm(float x){
  return __builtin_amdgcn_rcpf(1.f + __expf(-x));
}
__device__ __forceinline__ float tanh_f(float x){
  return 1.f - 2.f*__builtin_amdgcn_rcpf(1.f + __expf(2.f*x));
}

// ---- prep: E0g = per-thread-permuted bf16(emb @ w_ih0^T + biases) (verified r7) ----
__global__ void e0g_kernel(const float* __restrict__ emb, const float* __restrict__ w_ih0,
                           const float* __restrict__ b_ih0, const float* __restrict__ b_hh0,
                           short* __restrict__ E0g)
{
  int tid = blockIdx.x*blockDim.x + threadIdx.x;
  if (tid >= 64*NG) return;
  int v = tid / NG, n = tid % NG;
  const float4* er = (const float4*)(emb + (size_t)v*HD);
  const float4* wr = (const float4*)(w_ih0 + (size_t)n*HD);
  float s = 0.f;
#pragma unroll 4
  for (int k=0;k<HD/4;++k){
    float4 a = er[k], b = wr[k];
    s += a.x*b.x + a.y*b.y + a.z*b.z + a.w*b.w;
  }
  s += b_ih0[n];
  if (n < 512) s += b_hh0[n];
  int g = n >> 8, j = n & 255;
  int wid = j >> 5, c = (j >> 4) & 1, l15 = j & 15;
  E0g[(size_t)v*1024 + wid*128 + l15*8 + g*2 + c] = f2bf(s);
}

// ---- prep: pack weights into fragment-linear bf16 tiles (verified r1-7) ----
__global__ void pack_kernel(const float* __restrict__ w_hh0, const float* __restrict__ w_ih1,
                            const float* __restrict__ w_hh1, const float* __restrict__ w1,
                            const float* __restrict__ w2, short* __restrict__ pack)
{
  int tid = blockIdx.x*blockDim.x + threadIdx.x;
  if (tid >= 1336*64) return;
  int t = tid >> 6, lane = tid & 63;
  int l15 = lane & 15, lq = lane >> 4;
  const float* src = nullptr;
  bool zero = false;
  if (t < 1152){
    int m = t/384, tt = t%384, ct = tt/8, kt = tt%8;
    int n = ct*16 + l15;
    const float* Wm = (m==0) ? w_hh0 : (m==1 ? w_ih1 : w_hh1);
    src = Wm + (size_t)n*HD + kt*32 + lq*8;
  } else if (t < 1280){
    int tt = t - 1152, w = tt/16, rem = tt%16, ntt = rem/8, kt = rem%8;
    int n = w*32 + ntt*16 + l15;
    src = w1 + (size_t)n*HD + kt*32 + lq*8;
  } else {
    int tt = t - 1280, ntt = tt/8, kt = tt%8;
    int n = ntt*16 + l15;
    if (n < LOUT) src = w2 + (size_t)n*HD + kt*32 + lq*8;
    else zero = true;
  }
  bh8 o;
#pragma unroll
  for (int e=0;e<8;++e) o[e] = zero ? (short)0 : f2bf(src[e]);
  ((bh8*)pack)[tid] = o;
}

// ================= scan bodies (verified r7 logic, bid-relative) =================

__device__ __forceinline__ void layer0_body(
    int bid, const int* __restrict__ tokens, const short* __restrict__ E0g,
    const short* __restrict__ pack, const float* __restrict__ b_hh0,
    short* __restrict__ s0c, short* __restrict__ h0g, int tc, int Tc,
    short (&st)[2][16*264])
{
  const int tid = threadIdx.x;
  const int wid = tid >> 6;
  const int lane = tid & 63;
  const int l15 = lane & 15, lq = lane >> 4;
  const int b0 = bid * 16;

  bh8 W[3][2][8];
  {
    const bh8* pt = (const bh8*)pack;
#pragma unroll
    for (int g=0;g<3;++g)
#pragma unroll
      for (int c=0;c<2;++c)
#pragma unroll
        for (int kt=0;kt<8;++kt)
          W[g][c][kt] = pt[(size_t)((g*16 + wid*2 + c)*8 + kt)*64 + lane];
  }
  float bhn0[2];
#pragma unroll
  for (int c=0;c<2;++c) bhn0[c] = b_hh0[512 + wid*32 + c*16 + l15];

  if (tc == 0){
    for (int i=tid;i<16*264;i+=512) st[0][i] = 0;
  } else {
    for (int i=tid;i<16*256;i+=512)
      st[0][(i>>8)*264 + (i&255)] = h0g[(size_t)(b0 + (i>>8))*HD + (i&255)];
  }

  const int e0base = wid*128 + l15*8;
  bh8 ev[4];
  {
    const int tg0 = tc*Tc;
    int tokr[4];
#pragma unroll
    for (int r=0;r<4;++r) tokr[r] = tokens[(size_t)tg0*BTOT + b0 + lq*4 + r];
#pragma unroll
    for (int r=0;r<4;++r)
      ev[r] = *(const bh8*)(E0g + (size_t)tokr[r]*1024 + e0base);
  }
  __syncthreads();

  const f4 zf = {0.f,0.f,0.f,0.f};
  const int crow = tid >> 5, ccol8 = (tid & 31)*8;

#pragma unroll 1
  for (int t=0; t<Tc; ++t){
    const int p = t & 1;
    const int tg = tc*Tc + t;
    const int tn = (tg+1 < T_STEPS) ? tg+1 : T_STEPS-1;
    int tokn[4];
#pragma unroll
    for (int r=0;r<4;++r) tokn[r] = tokens[(size_t)tn*BTOT + b0 + lq*4 + r];
    f4 acc[3][2];
#pragma unroll
    for (int g=0;g<3;++g){ acc[g][0]=zf; acc[g][1]=zf; }
    {
      const short* sp = &st[p][l15*264 + lq*8];
#pragma unroll
      for (int kt=0;kt<8;++kt){
        bh8 a = *(const bh8*)(sp + kt*32);
#pragma unroll
        for (int g=0;g<3;++g){
          acc[g][0] = mfma16(a, W[g][0][kt], acc[g][0]);
          acc[g][1] = mfma16(a, W[g][1][kt], acc[g][1]);
        }
      }
    }
    if (t > 0){
      bh8 cv = *(const bh8*)(&st[p][crow*264 + ccol8]);
      *(bh8*)(s0c + ((size_t)(t-1)*BTOT + b0 + crow)*HD + ccol8) = cv;
    }
    {
      short* stw = st[p^1];
#pragma unroll
      for (int c=0;c<2;++c){
        const int jh = wid*32 + c*16 + l15;
#pragma unroll
        for (int r4=0;r4<4;++r4){
          const int row = lq*4 + r4;
          const float er = bf2f(ev[r4][c]);
          const float ez = bf2f(ev[r4][2+c]);
          const float en = bf2f(ev[r4][4+c]);
          const float rg = sigm(acc[0][c][r4] + er);
          const float zg = sigm(acc[1][c][r4] + ez);
          const float ng = tanh_f(en + rg*(acc[2][c][r4] + bhn0[c]));
          const float ho = bf2f(st[p][row*264 + jh]);
          const float h = ng + zg*(ho - ng);
          stw[row*264 + jh] = f2bf(h);
        }
      }
    }
#pragma unroll
    for (int r=0;r<4;++r)
      ev[r] = *(const bh8*)(E0g + (size_t)tokn[r]*1024 + e0base);
    __syncthreads();
  }
  {
    bh8 cv = *(const bh8*)(&st[Tc & 1][crow*264 + ccol8]);
    *(bh8*)(s0c + ((size_t)(Tc-1)*BTOT + b0 + crow)*HD + ccol8) = cv;
    *(bh8*)(h0g + ((size_t)(b0 + crow))*HD + ccol8) = cv;
  }
}

__device__ __forceinline__ void layer1_body(
    int bid, const int* __restrict__ lens, const short* __restrict__ gi1p,
    const short* __restrict__ pack, const float* __restrict__ b_hh1,
    short* __restrict__ h1g, short* __restrict__ outbuf, int tc, int Tc,
    short (&st)[2][16*264])
{
  const int tid = threadIdx.x;
  const int wid = tid >> 6;
  const int lane = tid & 63;
  const int l15 = lane & 15, lq = lane >> 4;
  const int b0 = bid * 16;
  const int bblk = bid;

  bh8 W[3][2][8];
  {
    const bh8* pt = (const bh8*)pack;
#pragma unroll
    for (int g=0;g<3;++g)
#pragma unroll
      for (int c=0;c<2;++c)
#pragma unroll
        for (int kt=0;kt<8;++kt)
          W[g][c][kt] = pt[(size_t)(768 + (g*16 + wid*2 + c)*8 + kt)*64 + lane];
  }
  float bhn1[2];
#pragma unroll
  for (int c=0;c<2;++c) bhn1[c] = b_hh1[512 + wid*32 + c*16 + l15];

  int mylens[4];
#pragma unroll
  for (int r=0;r<4;++r) mylens[r] = lens[b0 + lq*4 + r];

  if (tc == 0){
    for (int i=tid;i<16*264;i+=512) st[0][i] = 0;
  } else {
    for (int i=tid;i<16*256;i+=512)
      st[0][(i>>8)*264 + (i&255)] = h1g[(size_t)(b0 + (i>>8))*HD + (i&255)];
  }

  bh8 gv[3];
#pragma unroll
  for (int g=0;g<3;++g)
    gv[g] = *(const bh8*)(gi1p + ((size_t)bblk*512 + tid)*24 + g*8);
  __syncthreads();

  const f4 zf = {0.f,0.f,0.f,0.f};
  const int crow = tid >> 5, ccol8 = (tid & 31)*8;

#pragma unroll 1
  for (int t=0; t<Tc; ++t){
    const int p = t & 1;
    const int tg = tc*Tc + t;
    f4 acc[3][2];
#pragma unroll
    for (int g=0;g<3;++g){ acc[g][0]=zf; acc[g][1]=zf; }
    {
      const short* sp = &st[p][l15*264 + lq*8];
#pragma unroll
      for (int kt=0;kt<8;++kt){
        bh8 a = *(const bh8*)(sp + kt*32);
#pragma unroll
        for (int g=0;g<3;++g){
          acc[g][0] = mfma16(a, W[g][0][kt], acc[g][0]);
          acc[g][1] = mfma16(a, W[g][1][kt], acc[g][1]);
        }
      }
    }
    {
      short* stw = st[p^1];
#pragma unroll
      for (int c=0;c<2;++c){
        const int jh = wid*32 + c*16 + l15;
#pragma unroll
        for (int r4=0;r4<4;++r4){
          const int row = lq*4 + r4;
          const float gr = bf2f(gv[0][c*4+r4]);
          const float gz = bf2f(gv[1][c*4+r4]);
          const float gn = bf2f(gv[2][c*4+r4]);
          const float rg = sigm(acc[0][c][r4] + gr);
          const float zg = sigm(acc[1][c][r4] + gz);
          const float ng = tanh_f(gn + rg*(acc[2][c][r4] + bhn1[c]));
          const float ho = bf2f(st[p][row*264 + jh]);
          const float h = ng + zg*(ho - ng);
          const short hb = f2bf(h);
          stw[row*264 + jh] = hb;
          if (tg == mylens[r4]) outbuf[(size_t)(b0 + row)*HD + jh] = hb;
        }
      }
    }
    if (t+1 < Tc){
#pragma unroll
      for (int g=0;g<3;++g)
        gv[g] = *(const bh8*)(gi1p + (((size_t)(t+1)*128 + bblk)*512 + tid)*24 + g*8);
    }
    __syncthreads();
  }
  {
    bh8 cv = *(const bh8*)(&st[Tc & 1][crow*264 + ccol8]);
    *(bh8*)(h1g + ((size_t)(b0 + crow))*HD + ccol8) = cv;
  }
}

// ---- fat kernel: blocks 0-127 run layer0(tc0), blocks 128-255 run layer1(tc1) ----
__global__ __launch_bounds__(512, 1)
void scan_fat(const int* __restrict__ tokens, const short* __restrict__ E0g,
              const short* __restrict__ pack, const float* __restrict__ b_hh0,
              short* __restrict__ s0c, short* __restrict__ h0g,
              const int* __restrict__ lens, const short* __restrict__ gi1p,
              const float* __restrict__ b_hh1, short* __restrict__ h1g,
              short* __restrict__ outbuf, int tc0, int tc1, int Tc)
{
  __shared__ __align__(16) short st[2][16*264];
  const int bx = blockIdx.x;
  if (bx < 128){
    if (tc0 >= 0)
      layer0_body(bx, tokens, E0g, pack, b_hh0, s0c, h0g, tc0, Tc, st);
  } else {
    if (tc1 >= 0)
      layer1_body(bx - 128, lens, gi1p, pack, b_hh1, h1g, outbuf, tc1, Tc, st);
  }
}

// ---- phase B: gi1 GEMM (verified r7) ----
__global__ __launch_bounds__(256, 1)
void gi1_gemm(const short* __restrict__ s0c, const short* __restrict__ pack,
              const float* __restrict__ b_ih1, const float* __restrict__ b_hh1,
              short* __restrict__ gi1p, int NC)
{
  const int tid = threadIdx.x;
  const int wid = tid >> 6;
  const int lane = tid & 63;
  const int l15 = lane & 15, lq = lane >> 4;

  __shared__ __align__(16) short ab[2][16*264];
  __shared__ float bi[NG];
  for (int i=tid;i<NG;i+=256) bi[i] = b_ih1[i] + ((i < 512) ? b_hh1[i] : 0.f);

  bh8 W[12][8];
#pragma unroll
  for (int i=0;i<12;++i)
#pragma unroll
    for (int kt=0;kt<8;++kt)
      W[i][kt] = ((const bh8*)pack)[(size_t)(384 + (wid*12+i)*8 + kt)*64 + lane];

  int ci = blockIdx.x;
  if (ci >= NC) return;
  bh8 sr[2];
#pragma unroll
  for (int j=0;j<2;++j){
    int q = tid + j*256;
    sr[j] = *(const bh8*)(s0c + (size_t)ci*4096 + q*8);
  }
#pragma unroll
  for (int j=0;j<2;++j){
    int q = tid + j*256, row = q>>5, col8 = (q&31)*8;
    *(bh8*)(&ab[0][row*264 + col8]) = sr[j];
  }
  __syncthreads();

  const f4 zf = {0.f,0.f,0.f,0.f};
  int p = 0;
#pragma unroll 1
  for (; ci < NC; ci += gridDim.x){
    const int cin = ci + (int)gridDim.x;
    const bool more = (cin < NC);
    if (more){
#pragma unroll
      for (int j=0;j<2;++j){
        int q = tid + j*256;
        sr[j] = *(const bh8*)(s0c + (size_t)cin*4096 + q*8);
      }
    }
    f4 acc[12];
#pragma unroll
    for (int i=0;i<12;++i) acc[i] = zf;
    const short* sp = &ab[p][l15*264 + lq*8];
#pragma unroll
    for (int kt=0;kt<8;++kt){
      bh8 a = *(const bh8*)(sp + kt*32);
#pragma unroll
      for (int i=0;i<12;++i) acc[i] = mfma16(a, W[i][kt], acc[i]);
    }
#pragma unroll
    for (int i=0;i<12;++i){
      const int gc = (wid*12+i)*16 + l15;
      const int g = gc >> 8, j = gc & 255;
      const int widp = j >> 5, c = (j >> 4) & 1;
      const int tidp = widp*64 + lq*16 + l15;
      const float b = bi[gc];
      sh4 v;
#pragma unroll
      for (int r4=0;r4<4;++r4) v[r4] = f2bf(acc[i][r4] + b);
      *(sh4*)(gi1p + ((size_t)ci*512 + tidp)*24 + g*8 + c*4) = v;
    }
    if (more){
#pragma unroll
      for (int j=0;j<2;++j){
        int q = tid + j*256, row = q>>5, col8 = (q&31)*8;
        *(bh8*)(&ab[p^1][row*264 + col8]) = sr[j];
      }
    }
    p ^= 1;
    __syncthreads();
  }
}

// ---- phase D: head (verified r1-7) ----
__global__ __launch_bounds__(512, 1)
void head_kernel(const short* __restrict__ outbuf, const short* __restrict__ pack,
                 const float* __restrict__ b1, const float* __restrict__ b2,
                 float* __restrict__ out)
{
  const int tid = threadIdx.x;
  const int wid = tid >> 6;
  const int lane = tid & 63;
  const int l15 = lane & 15, lq = lane >> 4;
  const int b0 = blockIdx.x * 32;

  __shared__ __align__(16) short zA[32*264];
  __shared__ __align__(16) short zB[32*264];
  __shared__ float b1s[HD], b2s[112];
  if (tid < HD)  b1s[tid] = b1[tid];
  if (tid < 112) b2s[tid] = (tid < LOUT) ? b2[tid] : 0.f;

  for (int i=tid;i<32*256;i+=512){
    int row = i >> 8, col = i & 255;
    zA[row*264 + col] = outbuf[(size_t)(b0 + row)*HD + col];
  }
  __syncthreads();

  const f4 zf = {0.f,0.f,0.f,0.f};
  const int afrag = l15*264 + lq*8;
  constexpr int RT1 = 16*264;
  const bh8* packW1 = (const bh8*)pack + (size_t)(1152 + wid*16)*64 + lane;
  const bh8* packW2 = (const bh8*)pack + (size_t)(1280 + wid*8 )*64 + lane;

  {
    f4 az[2][2]; az[0][0]=zf; az[0][1]=zf; az[1][0]=zf; az[1][1]=zf;
#pragma unroll
    for (int kt=0;kt<8;++kt){
      bh8 a0 = *(const bh8*)(&zA[afrag + kt*32]);
      bh8 a1 = *(const bh8*)(&zA[afrag + RT1 + kt*32]);
#pragma unroll
      for (int nt=0;nt<2;++nt){
        bh8 b = packW1[(nt*8+kt)*64];
        az[nt][0] = mfma16(a0, b, az[nt][0]);
        az[nt][1] = mfma16(a1, b, az[nt][1]);
      }
    }
#pragma unroll
    for (int rt=0;rt<2;++rt)
#pragma unroll
      for (int nt=0;nt<2;++nt){
        const int jb = wid*32 + nt*16 + l15;
#pragma unroll
        for (int r4=0;r4<4;++r4){
          float v = az[nt][rt][r4] + b1s[jb];
          v = (v >= 0.f) ? v : 0.01f*v;     // LeakyReLU
          zB[(rt*16+lq*4+r4)*264 + jb] = f2bf(v);
        }
      }
  }
  __syncthreads();

  if (wid < 7){
    f4 acc2[2]; acc2[0]=zf; acc2[1]=zf;
#pragma unroll
    for (int kt=0;kt<8;++kt){
      bh8 a0 = *(const bh8*)(&zB[afrag + kt*32]);
      bh8 a1 = *(const bh8*)(&zB[afrag + RT1 + kt*32]);
      bh8 b = packW2[kt*64];
      acc2[0] = mfma16(a0, b, acc2[0]);
      acc2[1] = mfma16(a1, b, acc2[1]);
    }
    const int n2 = wid*16 + l15;
    if (n2 < LOUT){
#pragma unroll
      for (int rt=0;rt<2;++rt)
#pragma unroll
        for (int r4=0;r4<4;++r4)
          out[(size_t)(b0 + rt*16 + lq*4 + r4)*LOUT + n2] = acc2[rt][r4] + b2s[n2];
    }
  }
}

extern "C" void kernel_launch(void* const* d_in, const int* in_sizes, int n_in,
                              void* d_out, int out_size, void* d_ws, size_t ws_size,
                              hipStream_t stream)
{
  const int*   tokens = (const int*)  d_in[0];
  const int*   lens   = (const int*)  d_in[1];
  const float* emb    = (const float*)d_in[2];
  const float* w_ih0  = (const float*)d_in[3];
  const float* w_hh0  = (const float*)d_in[4];
  const float* b_ih0  = (const float*)d_in[5];
  const float* b_hh0  = (const float*)d_in[6];
  const float* w_ih1  = (const float*)d_in[7];
  const float* w_hh1  = (const float*)d_in[8];
  const float* b_ih1  = (const float*)d_in[9];
  const float* b_hh1  = (const float*)d_in[10];
  const float* w1     = (const float*)d_in[11];
  const float* b1     = (const float*)d_in[12];
  const float* w2     = (const float*)d_in[13];
  const float* b2     = (const float*)d_in[14];

  char* ws = (char*)d_ws;
  size_t off = 0;
  short* pack = (short*)(ws + off); off += (size_t)1336*1024;       // 1.34 MB
  short* E0g  = (short*)(ws + off); off += (size_t)64*1024*2;       // 128 KB
  short* h0g  = (short*)(ws + off); off += (size_t)BTOT*HD*2;       // 1 MB
  short* h1g  = (short*)(ws + off); off += (size_t)BTOT*HD*2;       // 1 MB
  short* outb = (short*)(ws + off); off += (size_t)BTOT*HD*2;       // 1 MB
  const size_t fixed = off;
  const size_t perT = (size_t)BTOT*HD*2 + (size_t)BTOT*NG*2;        // 4 MB / step
  int Tc = T_STEPS;
  while (Tc > 1 && fixed + (size_t)Tc*perT > ws_size) Tc >>= 1;
  short* s0c  = (short*)(ws + fixed);
  short* gi1p = (short*)(ws + fixed + (size_t)Tc*BTOT*HD*2);

  e0g_kernel <<<(64*NG + 255)/256,   256, 0, stream>>>(emb, w_ih0, b_ih0, b_hh0, E0g);
  pack_kernel<<<(1336*64 + 255)/256, 256, 0, stream>>>(w_hh0, w_ih1, w_hh1, w1, w2, pack);

  const int nch = T_STEPS / Tc;
  // software pipeline across chunks: F(k) = L0(k) || L1(k-1);  G(k) between.
  for (int k = 0; k <= nch; ++k){
    const int tc0 = (k < nch) ? k : -1;
    const int tc1 = k - 1;
    scan_fat<<<256, 512, 0, stream>>>(tokens, E0g, pack, b_hh0, s0c, h0g,
                                      lens, gi1p, b_hh1, h1g, outb, tc0, tc1, Tc);
    if (k < nch)
      gi1_gemm<<<256, 256, 0, stream>>>(s0c, pack, b_ih1, b_hh1, gi1p, Tc*BTOT/16);
  }
  head_kernel<<<BTOT/32, 512, 0, stream>>>(outb, pack, b1, b2, (float*)d_out);
}

// Round 9
// 605.479 us; speedup vs baseline: 8.9863x; 1.1160x over previous
//
#include <hip/hip_runtime.h>
#include <hip/hip_bf16.h>

typedef __attribute__((ext_vector_type(8))) short bh8;   // 8 x bf16 (4 VGPRs)
typedef __attribute__((ext_vector_type(4))) short sh4;   // 4 x bf16
typedef __attribute__((ext_vector_type(4))) float f4;    // MFMA accumulator

static constexpr int T_STEPS = 128;
static constexpr int BTOT    = 2048;
static constexpr int HD      = 256;
static constexpr int NG      = 768;   // 3*H
static constexpr int LOUT    = 100;

__device__ __forceinline__ short f2bf(float f){
  unsigned u = __builtin_bit_cast(unsigned, f);
  unsigned r = (u + 0x7FFFu + ((u >> 16) & 1u)) >> 16;   // RNE
  return (short)(unsigned short)r;
}
__device__ __forceinline__ float bf2f(short s){
  unsigned u = ((unsigned)(unsigned short)s) << 16;
  return __builtin_bit_cast(float, u);
}
__device__ __forceinline__ f4 mfma16(bh8 a, bh8 b, f4 c){
  return __builtin_amdgcn_mfma_f32_16x16x32_bf16(a, b, c, 0, 0, 0);
}
__device__ __forceinline__ float sigm(float x){
  return __builtin_amdgcn_rcpf(1.f + __expf(-x));
}
__device__ __forceinline__ float tanh_f(float x){
  return 1.f - 2.f*__builtin_amdgcn_rcpf(1.f + __expf(2.f*x));
}

// ---- prep: E0g = per-thread-permuted bf16(emb @ w_ih0^T + biases) (verified r7-8) ----
__global__ void e0g_kernel(const float* __restrict__ emb, const float* __restrict__ w_ih0,
                           const float* __restrict__ b_ih0, const float* __restrict__ b_hh0,
                           short* __restrict__ E0g)
{
  int tid = blockIdx.x*blockDim.x + threadIdx.x;
  if (tid >= 64*NG) return;
  int v = tid / NG, n = tid % NG;
  const float4* er = (const float4*)(emb + (size_t)v*HD);
  const float4* wr = (const float4*)(w_ih0 + (size_t)n*HD);
  float s = 0.f;
#pragma unroll 4
  for (int k=0;k<HD/4;++k){
    float4 a = er[k], b = wr[k];
    s += a.x*b.x + a.y*b.y + a.z*b.z + a.w*b.w;
  }
  s += b_ih0[n];
  if (n < 512) s += b_hh0[n];
  int g = n >> 8, j = n & 255;
  int wid = j >> 5, c = (j >> 4) & 1, l15 = j & 15;
  E0g[(size_t)v*1024 + wid*128 + l15*8 + g*2 + c] = f2bf(s);
}

// ---- prep: pack weights into fragment-linear bf16 tiles (verified r1-8) ----
__global__ void pack_kernel(const float* __restrict__ w_hh0, const float* __restrict__ w_ih1,
                            const float* __restrict__ w_hh1, const float* __restrict__ w1,
                            const float* __restrict__ w2, short* __restrict__ pack)
{
  int tid = blockIdx.x*blockDim.x + threadIdx.x;
  if (tid >= 1336*64) return;
  int t = tid >> 6, lane = tid & 63;
  int l15 = lane & 15, lq = lane >> 4;
  const float* src = nullptr;
  bool zero = false;
  if (t < 1152){
    int m = t/384, tt = t%384, ct = tt/8, kt = tt%8;
    int n = ct*16 + l15;
    const float* Wm = (m==0) ? w_hh0 : (m==1 ? w_ih1 : w_hh1);
    src = Wm + (size_t)n*HD + kt*32 + lq*8;
  } else if (t < 1280){
    int tt = t - 1152, w = tt/16, rem = tt%16, ntt = rem/8, kt = rem%8;
    int n = w*32 + ntt*16 + l15;
    src = w1 + (size_t)n*HD + kt*32 + lq*8;
  } else {
    int tt = t - 1280, ntt = tt/8, kt = tt%8;
    int n = ntt*16 + l15;
    if (n < LOUT) src = w2 + (size_t)n*HD + kt*32 + lq*8;
    else zero = true;
  }
  bh8 o;
#pragma unroll
  for (int e=0;e<8;++e) o[e] = zero ? (short)0 : f2bf(src[e]);
  ((bh8*)pack)[tid] = o;
}

// ================= scan bodies (r8 logic + f32 h-carry) =================

__device__ __forceinline__ void layer0_body(
    int bid, const int* __restrict__ tokens, const short* __restrict__ E0g,
    const short* __restrict__ pack, const float* __restrict__ b_hh0,
    short* __restrict__ s0c, short* __restrict__ h0g, int tc, int Tc,
    short (&st)[2][16*264])
{
  const int tid = threadIdx.x;
  const int wid = tid >> 6;
  const int lane = tid & 63;
  const int l15 = lane & 15, lq = lane >> 4;
  const int b0 = bid * 16;

  bh8 W[3][2][8];
  {
    const bh8* pt = (const bh8*)pack;
#pragma unroll
    for (int g=0;g<3;++g)
#pragma unroll
      for (int c=0;c<2;++c)
#pragma unroll
        for (int kt=0;kt<8;++kt)
          W[g][c][kt] = pt[(size_t)((g*16 + wid*2 + c)*8 + kt)*64 + lane];
  }
  float bhn0[2];
#pragma unroll
  for (int c=0;c<2;++c) bhn0[c] = b_hh0[512 + wid*32 + c*16 + l15];

  float h0s[2][4];
  if (tc == 0){
#pragma unroll
    for (int c=0;c<2;++c)
#pragma unroll
      for (int r=0;r<4;++r) h0s[c][r] = 0.f;
    for (int i=tid;i<16*264;i+=512) st[0][i] = 0;
  } else {
#pragma unroll
    for (int c=0;c<2;++c)
#pragma unroll
      for (int r=0;r<4;++r)
        h0s[c][r] = bf2f(h0g[(size_t)(b0 + lq*4 + r)*HD + wid*32 + c*16 + l15]);
    for (int i=tid;i<16*256;i+=512)
      st[0][(i>>8)*264 + (i&255)] = h0g[(size_t)(b0 + (i>>8))*HD + (i&255)];
  }

  const int e0base = wid*128 + l15*8;
  bh8 ev[4];
  {
    const int tg0 = tc*Tc;
    int tokr[4];
#pragma unroll
    for (int r=0;r<4;++r) tokr[r] = tokens[(size_t)tg0*BTOT + b0 + lq*4 + r];
#pragma unroll
    for (int r=0;r<4;++r)
      ev[r] = *(const bh8*)(E0g + (size_t)tokr[r]*1024 + e0base);
  }
  __syncthreads();

  const f4 zf = {0.f,0.f,0.f,0.f};
  const int crow = tid >> 5, ccol8 = (tid & 31)*8;

#pragma unroll 1
  for (int t=0; t<Tc; ++t){
    const int p = t & 1;
    const int tg = tc*Tc + t;
    const int tn = (tg+1 < T_STEPS) ? tg+1 : T_STEPS-1;
    int tokn[4];
#pragma unroll
    for (int r=0;r<4;++r) tokn[r] = tokens[(size_t)tn*BTOT + b0 + lq*4 + r];
    f4 acc[3][2];
#pragma unroll
    for (int g=0;g<3;++g){ acc[g][0]=zf; acc[g][1]=zf; }
    {
      const short* sp = &st[p][l15*264 + lq*8];
#pragma unroll
      for (int kt=0;kt<8;++kt){
        bh8 a = *(const bh8*)(sp + kt*32);
#pragma unroll
        for (int g=0;g<3;++g){
          acc[g][0] = mfma16(a, W[g][0][kt], acc[g][0]);
          acc[g][1] = mfma16(a, W[g][1][kt], acc[g][1]);
        }
      }
    }
    if (t > 0){
      bh8 cv = *(const bh8*)(&st[p][crow*264 + ccol8]);
      *(bh8*)(s0c + ((size_t)(t-1)*BTOT + b0 + crow)*HD + ccol8) = cv;
    }
    {
      short* stw = st[p^1];
#pragma unroll
      for (int c=0;c<2;++c){
        const int jh = wid*32 + c*16 + l15;
#pragma unroll
        for (int r4=0;r4<4;++r4){
          const int row = lq*4 + r4;
          const float er = bf2f(ev[r4][c]);
          const float ez = bf2f(ev[r4][2+c]);
          const float en = bf2f(ev[r4][4+c]);
          const float rg = sigm(acc[0][c][r4] + er);
          const float zg = sigm(acc[1][c][r4] + ez);
          const float ng = tanh_f(en + rg*(acc[2][c][r4] + bhn0[c]));
          const float h = ng + zg*(h0s[c][r4] - ng);
          h0s[c][r4] = h;
          stw[row*264 + jh] = f2bf(h);
        }
      }
    }
#pragma unroll
    for (int r=0;r<4;++r)
      ev[r] = *(const bh8*)(E0g + (size_t)tokn[r]*1024 + e0base);
    __syncthreads();
  }
  {
    bh8 cv = *(const bh8*)(&st[Tc & 1][crow*264 + ccol8]);
    *(bh8*)(s0c + ((size_t)(Tc-1)*BTOT + b0 + crow)*HD + ccol8) = cv;
    *(bh8*)(h0g + ((size_t)(b0 + crow))*HD + ccol8) = cv;
  }
}

__device__ __forceinline__ void layer1_body(
    int bid, const int* __restrict__ lens, const short* __restrict__ gi1p,
    const short* __restrict__ pack, const float* __restrict__ b_hh1,
    short* __restrict__ h1g, short* __restrict__ outbuf, int tc, int Tc,
    short (&st)[2][16*264])
{
  const int tid = threadIdx.x;
  const int wid = tid >> 6;
  const int lane = tid & 63;
  const int l15 = lane & 15, lq = lane >> 4;
  const int b0 = bid * 16;
  const int bblk = bid;

  bh8 W[3][2][8];
  {
    const bh8* pt = (const bh8*)pack;
#pragma unroll
    for (int g=0;g<3;++g)
#pragma unroll
      for (int c=0;c<2;++c)
#pragma unroll
        for (int kt=0;kt<8;++kt)
          W[g][c][kt] = pt[(size_t)(768 + (g*16 + wid*2 + c)*8 + kt)*64 + lane];
  }
  float bhn1[2];
#pragma unroll
  for (int c=0;c<2;++c) bhn1[c] = b_hh1[512 + wid*32 + c*16 + l15];

  int mylens[4];
#pragma unroll
  for (int r=0;r<4;++r) mylens[r] = lens[b0 + lq*4 + r];

  float h1s[2][4];
  if (tc == 0){
#pragma unroll
    for (int c=0;c<2;++c)
#pragma unroll
      for (int r=0;r<4;++r) h1s[c][r] = 0.f;
    for (int i=tid;i<16*264;i+=512) st[0][i] = 0;
  } else {
#pragma unroll
    for (int c=0;c<2;++c)
#pragma unroll
      for (int r=0;r<4;++r)
        h1s[c][r] = bf2f(h1g[(size_t)(b0 + lq*4 + r)*HD + wid*32 + c*16 + l15]);
    for (int i=tid;i<16*256;i+=512)
      st[0][(i>>8)*264 + (i&255)] = h1g[(size_t)(b0 + (i>>8))*HD + (i&255)];
  }

  bh8 gv[3];
#pragma unroll
  for (int g=0;g<3;++g)
    gv[g] = *(const bh8*)(gi1p + ((size_t)bblk*512 + tid)*24 + g*8);
  __syncthreads();

  const f4 zf = {0.f,0.f,0.f,0.f};
  const int crow = tid >> 5, ccol8 = (tid & 31)*8;

#pragma unroll 1
  for (int t=0; t<Tc; ++t){
    const int p = t & 1;
    const int tg = tc*Tc + t;
    f4 acc[3][2];
#pragma unroll
    for (int g=0;g<3;++g){ acc[g][0]=zf; acc[g][1]=zf; }
    {
      const short* sp = &st[p][l15*264 + lq*8];
#pragma unroll
      for (int kt=0;kt<8;++kt){
        bh8 a = *(const bh8*)(sp + kt*32);
#pragma unroll
        for (int g=0;g<3;++g){
          acc[g][0] = mfma16(a, W[g][0][kt], acc[g][0]);
          acc[g][1] = mfma16(a, W[g][1][kt], acc[g][1]);
        }
      }
    }
    {
      short* stw = st[p^1];
#pragma unroll
      for (int c=0;c<2;++c){
        const int jh = wid*32 + c*16 + l15;
#pragma unroll
        for (int r4=0;r4<4;++r4){
          const int row = lq*4 + r4;
          const float gr = bf2f(gv[0][c*4+r4]);
          const float gz = bf2f(gv[1][c*4+r4]);
          const float gn = bf2f(gv[2][c*4+r4]);
          const float rg = sigm(acc[0][c][r4] + gr);
          const float zg = sigm(acc[1][c][r4] + gz);
          const float ng = tanh_f(gn + rg*(acc[2][c][r4] + bhn1[c]));
          const float h = ng + zg*(h1s[c][r4] - ng);
          h1s[c][r4] = h;
          const short hb = f2bf(h);
          stw[row*264 + jh] = hb;
          if (tg == mylens[r4]) outbuf[(size_t)(b0 + row)*HD + jh] = hb;
        }
      }
    }
    if (t+1 < Tc){
#pragma unroll
      for (int g=0;g<3;++g)
        gv[g] = *(const bh8*)(gi1p + (((size_t)(t+1)*128 + bblk)*512 + tid)*24 + g*8);
    }
    __syncthreads();
  }
  {
    bh8 cv = *(const bh8*)(&st[Tc & 1][crow*264 + ccol8]);
    *(bh8*)(h1g + ((size_t)(b0 + crow))*HD + ccol8) = cv;
  }
}

// ---- fat kernel: blocks 0-127 run layer0(tc0), blocks 128-255 run layer1(tc1) ----
__global__ __launch_bounds__(512, 1)
void scan_fat(const int* __restrict__ tokens, const short* __restrict__ E0g,
              const short* __restrict__ pack, const float* __restrict__ b_hh0,
              short* __restrict__ s0c, short* __restrict__ h0g,
              const int* __restrict__ lens, const short* __restrict__ gi1p,
              const float* __restrict__ b_hh1, short* __restrict__ h1g,
              short* __restrict__ outbuf, int tc0, int tc1, int Tc)
{
  __shared__ __align__(16) short st[2][16*264];
  const int bx = blockIdx.x;
  if (bx < 128){
    if (tc0 >= 0)
      layer0_body(bx, tokens, E0g, pack, b_hh0, s0c, h0g, tc0, Tc, st);
  } else {
    if (tc1 >= 0)
      layer1_body(bx - 128, lens, gi1p, pack, b_hh1, h1g, outbuf, tc1, Tc, st);
  }
}

// ---- phase B: gi1 GEMM. 512 thr / 8 waves (2 waves/SIMD); wave owns 96 gate-cols. ----
__global__ __launch_bounds__(512, 1)
void gi1_gemm(const short* __restrict__ s0c, const short* __restrict__ pack,
              const float* __restrict__ b_ih1, const float* __restrict__ b_hh1,
              short* __restrict__ gi1p, int NC)
{
  const int tid = threadIdx.x;
  const int wid = tid >> 6;
  const int lane = tid & 63;
  const int l15 = lane & 15, lq = lane >> 4;

  __shared__ __align__(16) short ab[2][16*264];

  bh8 W[6][8];
#pragma unroll
  for (int i=0;i<6;++i)
#pragma unroll
    for (int kt=0;kt<8;++kt)
      W[i][kt] = ((const bh8*)pack)[(size_t)(384 + (wid*6+i)*8 + kt)*64 + lane];

  float bi[6];
  int offo[6];
#pragma unroll
  for (int i=0;i<6;++i){
    const int gc = (wid*6+i)*16 + l15;
    bi[i] = b_ih1[gc] + ((gc < 512) ? b_hh1[gc] : 0.f);
    const int g = gc >> 8, j = gc & 255;
    const int widp = j >> 5, c = (j >> 4) & 1;
    const int tidp = widp*64 + lq*16 + l15;
    offo[i] = tidp*24 + g*8 + c*4;
  }

  int ci = blockIdx.x;
  if (ci >= NC) return;
  // stage first chunk: 512 threads x 1 bh8 = 16 rows x 256 cols
  bh8 sr = *(const bh8*)(s0c + (size_t)ci*4096 + tid*8);
  *(bh8*)(&ab[0][(tid>>5)*264 + (tid&31)*8]) = sr;
  __syncthreads();

  const f4 zf = {0.f,0.f,0.f,0.f};
  int p = 0;
#pragma unroll 1
  for (; ci < NC; ci += gridDim.x){
    const int cin = ci + (int)gridDim.x;
    const bool more = (cin < NC);
    if (more) sr = *(const bh8*)(s0c + (size_t)cin*4096 + tid*8);
    f4 acc[6];
#pragma unroll
    for (int i=0;i<6;++i) acc[i] = zf;
    const short* sp = &ab[p][l15*264 + lq*8];
#pragma unroll
    for (int kt=0;kt<8;++kt){
      bh8 a = *(const bh8*)(sp + kt*32);
#pragma unroll
      for (int i=0;i<6;++i) acc[i] = mfma16(a, W[i][kt], acc[i]);
    }
#pragma unroll
    for (int i=0;i<6;++i){
      sh4 v;
#pragma unroll
      for (int r4=0;r4<4;++r4) v[r4] = f2bf(acc[i][r4] + bi[i]);
      *(sh4*)(gi1p + (size_t)ci*512*24 + offo[i]) = v;
    }
    if (more)
      *(bh8*)(&ab[p^1][(tid>>5)*264 + (tid&31)*8]) = sr;
    p ^= 1;
    __syncthreads();
  }
}

// ---- phase D: head (verified r1-8) ----
__global__ __launch_bounds__(512, 1)
void head_kernel(const short* __restrict__ outbuf, const short* __restrict__ pack,
                 const float* __restrict__ b1, const float* __restrict__ b2,
                 float* __restrict__ out)
{
  const int tid = threadIdx.x;
  const int wid = tid >> 6;
  const int lane = tid & 63;
  const int l15 = lane & 15, lq = lane >> 4;
  const int b0 = blockIdx.x * 32;

  __shared__ __align__(16) short zA[32*264];
  __shared__ __align__(16) short zB[32*264];
  __shared__ float b1s[HD], b2s[112];
  if (tid < HD)  b1s[tid] = b1[tid];
  if (tid < 112) b2s[tid] = (tid < LOUT) ? b2[tid] : 0.f;

  for (int i=tid;i<32*256;i+=512){
    int row = i >> 8, col = i & 255;
    zA[row*264 + col] = outbuf[(size_t)(b0 + row)*HD + col];
  }
  __syncthreads();

  const f4 zf = {0.f,0.f,0.f,0.f};
  const int afrag = l15*264 + lq*8;
  constexpr int RT1 = 16*264;
  const bh8* packW1 = (const bh8*)pack + (size_t)(1152 + wid*16)*64 + lane;
  const bh8* packW2 = (const bh8*)pack + (size_t)(1280 + wid*8 )*64 + lane;

  {
    f4 az[2][2]; az[0][0]=zf; az[0][1]=zf; az[1][0]=zf; az[1][1]=zf;
#pragma unroll
    for (int kt=0;kt<8;++kt){
      bh8 a0 = *(const bh8*)(&zA[afrag + kt*32]);
      bh8 a1 = *(const bh8*)(&zA[afrag + RT1 + kt*32]);
#pragma unroll
      for (int nt=0;nt<2;++nt){
        bh8 b = packW1[(nt*8+kt)*64];
        az[nt][0] = mfma16(a0, b, az[nt][0]);
        az[nt][1] = mfma16(a1, b, az[nt][1]);
      }
    }
#pragma unroll
    for (int rt=0;rt<2;++rt)
#pragma unroll
      for (int nt=0;nt<2;++nt){
        const int jb = wid*32 + nt*16 + l15;
#pragma unroll
        for (int r4=0;r4<4;++r4){
          float v = az[nt][rt][r4] + b1s[jb];
          v = (v >= 0.f) ? v : 0.01f*v;     // LeakyReLU
          zB[(rt*16+lq*4+r4)*264 + jb] = f2bf(v);
        }
      }
  }
  __syncthreads();

  if (wid < 7){
    f4 acc2[2]; acc2[0]=zf; acc2[1]=zf;
#pragma unroll
    for (int kt=0;kt<8;++kt){
      bh8 a0 = *(const bh8*)(&zB[afrag + kt*32]);
      bh8 a1 = *(const bh8*)(&zB[afrag + RT1 + kt*32]);
      bh8 b = packW2[kt*64];
      acc2[0] = mfma16(a0, b, acc2[0]);
      acc2[1] = mfma16(a1, b, acc2[1]);
    }
    const int n2 = wid*16 + l15;
    if (n2 < LOUT){
#pragma unroll
      for (int rt=0;rt<2;++rt)
#pragma unroll
        for (int r4=0;r4<4;++r4)
          out[(size_t)(b0 + rt*16 + lq*4 + r4)*LOUT + n2] = acc2[rt][r4] + b2s[n2];
    }
  }
}

extern "C" void kernel_launch(void* const* d_in, const int* in_sizes, int n_in,
                              void* d_out, int out_size, void* d_ws, size_t ws_size,
                              hipStream_t stream)
{
  const int*   tokens = (const int*)  d_in[0];
  const int*   lens   = (const int*)  d_in[1];
  const float* emb    = (const float*)d_in[2];
  const float* w_ih0  = (const float*)d_in[3];
  const float* w_hh0  = (const float*)d_in[4];
  const float* b_ih0  = (const float*)d_in[5];
  const float* b_hh0  = (const float*)d_in[6];
  const float* w_ih1  = (const float*)d_in[7];
  const float* w_hh1  = (const float*)d_in[8];
  const float* b_ih1  = (const float*)d_in[9];
  const float* b_hh1  = (const float*)d_in[10];
  const float* w1     = (const float*)d_in[11];
  const float* b1     = (const float*)d_in[12];
  const float* w2     = (const float*)d_in[13];
  const float* b2     = (const float*)d_in[14];

  char* ws = (char*)d_ws;
  size_t off = 0;
  short* pack = (short*)(ws + off); off += (size_t)1336*1024;       // 1.34 MB
  short* E0g  = (short*)(ws + off); off += (size_t)64*1024*2;       // 128 KB
  short* h0g  = (short*)(ws + off); off += (size_t)BTOT*HD*2;       // 1 MB
  short* h1g  = (short*)(ws + off); off += (size_t)BTOT*HD*2;       // 1 MB
  short* outb = (short*)(ws + off); off += (size_t)BTOT*HD*2;       // 1 MB
  const size_t fixed = off;
  const size_t perT = (size_t)BTOT*HD*2 + (size_t)BTOT*NG*2;        // 4 MB / step
  int Tc = T_STEPS;
  while (Tc > 1 && fixed + (size_t)Tc*perT > ws_size) Tc >>= 1;
  if (Tc > 32) Tc = 32;                                             // pipeline depth cap
  short* s0c  = (short*)(ws + fixed);
  short* gi1p = (short*)(ws + fixed + (size_t)Tc*BTOT*HD*2);

  e0g_kernel <<<(64*NG + 255)/256,   256, 0, stream>>>(emb, w_ih0, b_ih0, b_hh0, E0g);
  pack_kernel<<<(1336*64 + 255)/256, 256, 0, stream>>>(w_hh0, w_ih1, w_hh1, w1, w2, pack);

  const int nch = T_STEPS / Tc;
  // software pipeline across chunks: F(k) = L0(k) || L1(k-1);  G(k) between.
  for (int k = 0; k <= nch; ++k){
    const int tc0 = (k < nch) ? k : -1;
    const int tc1 = k - 1;
    scan_fat<<<256, 512, 0, stream>>>(tokens, E0g, pack, b_hh0, s0c, h0g,
                                      lens, gi1p, b_hh1, h1g, outb, tc0, tc1, Tc);
    if (k < nch)
      gi1_gemm<<<256, 512, 0, stream>>>(s0c, pack, b_ih1, b_hh1, gi1p, Tc*BTOT/16);
  }
  head_kernel<<<BTOT/32, 512, 0, stream>>>(outb, pack, b1, b2, (float*)d_out);
}